// Round 1
// baseline (256.649 us; speedup 1.0000x reference)
//
#include <hip/hip_runtime.h>
#include <cstddef>

#define NN 512
#define CC 64
#define BT 48

// workspace float offsets
#define OFF_BMIN 16
#define NBLK_MM  3072
#define OFF_BMAX (OFF_BMIN + NBLK_MM)
#define OFF_H    8192
#define SZ_Y     (BT * NN * CC)
#define OFF_Y1   (OFF_H + SZ_Y)
#define OFF_YA   (OFF_Y1 + SZ_Y)
#define OFF_YB   (OFF_YA + SZ_Y)
#define OFF_P    (OFF_YB + SZ_Y)
#define OFF_CS   (OFF_P + BT * 4 * CC * CC)

__device__ __forceinline__ void fma16(float acc[4][4], float4 a4, float4 b4) {
  const float a[4] = {a4.x, a4.y, a4.z, a4.w};
  const float b[4] = {b4.x, b4.y, b4.z, b4.w};
#pragma unroll
  for (int i = 0; i < 4; ++i)
#pragma unroll
    for (int j = 0; j < 4; ++j)
      acc[i][j] = fmaf(a[i], b[j], acc[i][j]);
}

// Shared epilogue: store tile tv to Yout, then Out += tv @ W (K=64 in-block).
__device__ __forceinline__ void epilogue_store_acc(
    float tv[4][4], const float* __restrict__ W,
    float (*Ts)[68], float (*Wl)[68],
    float* __restrict__ Yout, float* __restrict__ Out,
    size_t obase, int ty, int tx, int tid)
{
#pragma unroll
  for (int i = 0; i < 4; ++i) {
    float4 o = {tv[i][0], tv[i][1], tv[i][2], tv[i][3]};
    *(float4*)(Yout + obase + (size_t)(ty * 4 + i) * CC + tx * 4) = o;
  }
  __syncthreads();  // done reading main-loop smem before reuse
#pragma unroll
  for (int j = 0; j < 4; ++j) {
    int idx = tid + 256 * j;
    int r = idx >> 4, c4 = idx & 15;
    *(float4*)&Wl[r][c4 * 4] = *(const float4*)(W + idx * 4);
  }
#pragma unroll
  for (int i = 0; i < 4; ++i)
#pragma unroll
    for (int j = 0; j < 4; ++j)
      Ts[ty * 4 + i][tx * 4 + j] = tv[i][j];
  __syncthreads();
  float oacc[4][4] = {};
  for (int k = 0; k < CC; ++k) {
    float4 b4 = *(const float4*)&Wl[k][tx * 4];
    float4 a4v = {Ts[ty * 4 + 0][k], Ts[ty * 4 + 1][k],
                  Ts[ty * 4 + 2][k], Ts[ty * 4 + 3][k]};
    fma16(oacc, a4v, b4);
  }
#pragma unroll
  for (int i = 0; i < 4; ++i) {
    float* op = Out + obase + (size_t)(ty * 4 + i) * CC + tx * 4;
    float4 o = *(const float4*)op;
    o.x += oacc[i][0]; o.y += oacc[i][1]; o.z += oacc[i][2]; o.w += oacc[i][3];
    *(float4*)op = o;
  }
}

// Out[bt, r, c] = sum_k X[bt, r, k] * (W1[k,c] + W2[k,c])   (K = 64)
__global__ __launch_bounds__(256) void k_small_mm(
    const float* __restrict__ X, const float* __restrict__ W1,
    const float* __restrict__ W2, float* __restrict__ Out)
{
  __shared__ float Xs[CC][68];  // transposed: Xs[k][r]
  __shared__ float Ws[CC][68];  // natural:    Ws[k][c]
  const int tid = threadIdx.x;
  const int ty = tid >> 4, tx = tid & 15;
  const size_t base = ((size_t)blockIdx.y * NN + blockIdx.x * 64) * CC;
  const float* Xb = X + base;
#pragma unroll
  for (int j = 0; j < 4; ++j) {
    int idx = tid + 256 * j;
    int r = idx >> 4, c4 = idx & 15;
    float4 v = *(const float4*)(Xb + (size_t)r * CC + c4 * 4);
    Xs[c4 * 4 + 0][r] = v.x; Xs[c4 * 4 + 1][r] = v.y;
    Xs[c4 * 4 + 2][r] = v.z; Xs[c4 * 4 + 3][r] = v.w;
    float4 w = *(const float4*)(W1 + idx * 4);
    if (W2) {
      float4 w2 = *(const float4*)(W2 + idx * 4);
      w.x += w2.x; w.y += w2.y; w.z += w2.z; w.w += w2.w;
    }
    *(float4*)&Ws[r][c4 * 4] = w;
  }
  __syncthreads();
  float acc[4][4] = {};
  for (int k = 0; k < CC; ++k)
    fma16(acc, *(const float4*)&Xs[k][ty * 4], *(const float4*)&Ws[k][tx * 4]);
  float* Ob = Out + base;
#pragma unroll
  for (int i = 0; i < 4; ++i) {
    float4 o = {acc[i][0], acc[i][1], acc[i][2], acc[i][3]};
    *(float4*)(Ob + (size_t)(ty * 4 + i) * CC + tx * 4) = o;
  }
}

// Tile of wd_raw = H[bt] @ x[bt]^T ; per-block min/max to ws arrays.
__global__ __launch_bounds__(256) void k_minmax(
    const float* __restrict__ H, const float* __restrict__ X,
    float* __restrict__ wsf)
{
  __shared__ float Hs[CC][68];
  __shared__ float Xs[CC][68];
  __shared__ float red[8];
  const int tid = threadIdx.x;
  const int ty = tid >> 4, tx = tid & 15;
  const int bt = blockIdx.z;
  const float* Hb = H + ((size_t)bt * NN + blockIdx.x * 64) * CC;
  const float* Xb = X + ((size_t)bt * NN + blockIdx.y * 64) * CC;
#pragma unroll
  for (int j = 0; j < 4; ++j) {
    int idx = tid + 256 * j;
    int r = idx >> 4, c4 = idx & 15;
    float4 v = *(const float4*)(Hb + (size_t)r * CC + c4 * 4);
    Hs[c4 * 4 + 0][r] = v.x; Hs[c4 * 4 + 1][r] = v.y;
    Hs[c4 * 4 + 2][r] = v.z; Hs[c4 * 4 + 3][r] = v.w;
    float4 u = *(const float4*)(Xb + (size_t)r * CC + c4 * 4);
    Xs[c4 * 4 + 0][r] = u.x; Xs[c4 * 4 + 1][r] = u.y;
    Xs[c4 * 4 + 2][r] = u.z; Xs[c4 * 4 + 3][r] = u.w;
  }
  __syncthreads();
  float acc[4][4] = {};
  for (int k = 0; k < CC; ++k)
    fma16(acc, *(const float4*)&Hs[k][ty * 4], *(const float4*)&Xs[k][tx * 4]);
  float mn = acc[0][0], mx = acc[0][0];
#pragma unroll
  for (int i = 0; i < 4; ++i)
#pragma unroll
    for (int j = 0; j < 4; ++j) {
      mn = fminf(mn, acc[i][j]);
      mx = fmaxf(mx, acc[i][j]);
    }
  for (int off = 32; off; off >>= 1) {
    mn = fminf(mn, __shfl_xor(mn, off));
    mx = fmaxf(mx, __shfl_xor(mx, off));
  }
  if ((tid & 63) == 0) { red[tid >> 6] = mn; red[4 + (tid >> 6)] = mx; }
  __syncthreads();
  if (tid == 0) {
    mn = fminf(fminf(red[0], red[1]), fminf(red[2], red[3]));
    mx = fmaxf(fmaxf(red[4], red[5]), fmaxf(red[6], red[7]));
    int blk = ((bt * 8) + blockIdx.x) * 8 + blockIdx.y;
    wsf[OFF_BMIN + blk] = mn;
    wsf[OFF_BMAX + blk] = mx;
  }
}

// Reduce block min/max -> s = 1/((max+min)*N^2), c = min*s  at wsf[0],wsf[1]
__global__ __launch_bounds__(256) void k_reduce(float* __restrict__ wsf)
{
  const int tid = threadIdx.x;
  float mn = 3.4e38f, mx = -3.4e38f;
  for (int i = tid; i < NBLK_MM; i += 256) {
    mn = fminf(mn, wsf[OFF_BMIN + i]);
    mx = fmaxf(mx, wsf[OFF_BMAX + i]);
  }
  for (int off = 32; off; off >>= 1) {
    mn = fminf(mn, __shfl_xor(mn, off));
    mx = fmaxf(mx, __shfl_xor(mx, off));
  }
  __shared__ float red[8];
  if ((tid & 63) == 0) { red[tid >> 6] = mn; red[4 + (tid >> 6)] = mx; }
  __syncthreads();
  if (tid == 0) {
    mn = fminf(fminf(red[0], red[1]), fminf(red[2], red[3]));
    mx = fmaxf(fmaxf(red[4], red[5]), fmaxf(red[6], red[7]));
    float gmaxf = mx + mn;                      // max(wd_raw + gmin)
    float s = 1.0f / gmaxf / 262144.0f;         // /max /N^2
    wsf[0] = s;
    wsf[1] = mn * s;
  }
}

// T = alpha*(A @ S[bt]) + beta*R[bt]; store T; Out += T @ W.  A: (NN,NN)
__global__ __launch_bounds__(256) void k_bigmm(
    const float* __restrict__ A, const float* __restrict__ S,
    const float* __restrict__ R, const float* __restrict__ W,
    float alpha, float beta,
    float* __restrict__ Tout, float* __restrict__ Out)
{
  __shared__ float As[CC][68];  // transposed chunk of A
  __shared__ float Bs[CC][68];  // natural chunk of S
  __shared__ float Ts[CC][68];
  const int tid = threadIdx.x;
  const int ty = tid >> 4, tx = tid & 15;
  const int bt = blockIdx.y;
  const int i0 = blockIdx.x * 64;
  float acc[4][4] = {};
  for (int kk = 0; kk < NN; kk += 64) {
#pragma unroll
    for (int j = 0; j < 4; ++j) {
      int idx = tid + 256 * j;
      int r = idx >> 4, c4 = idx & 15;
      float4 v = *(const float4*)(A + (size_t)(i0 + r) * NN + kk + c4 * 4);
      As[c4 * 4 + 0][r] = v.x; As[c4 * 4 + 1][r] = v.y;
      As[c4 * 4 + 2][r] = v.z; As[c4 * 4 + 3][r] = v.w;
      float4 sv = *(const float4*)(S + ((size_t)bt * NN + kk + r) * CC + c4 * 4);
      *(float4*)&Bs[r][c4 * 4] = sv;
    }
    __syncthreads();
    for (int k = 0; k < 64; ++k)
      fma16(acc, *(const float4*)&As[k][ty * 4], *(const float4*)&Bs[k][tx * 4]);
    __syncthreads();
  }
  const size_t obase = ((size_t)bt * NN + i0) * CC;
  float tv[4][4];
  if (R) {
#pragma unroll
    for (int i = 0; i < 4; ++i) {
      float4 rv = *(const float4*)(R + obase + (size_t)(ty * 4 + i) * CC + tx * 4);
      tv[i][0] = alpha * acc[i][0] + beta * rv.x;
      tv[i][1] = alpha * acc[i][1] + beta * rv.y;
      tv[i][2] = alpha * acc[i][2] + beta * rv.z;
      tv[i][3] = alpha * acc[i][3] + beta * rv.w;
    }
  } else {
#pragma unroll
    for (int i = 0; i < 4; ++i)
#pragma unroll
      for (int j = 0; j < 4; ++j)
        tv[i][j] = alpha * acc[i][j];
  }
  epilogue_store_acc(tv, W, Ts, As, Tout, Out, obase, ty, tx, tid);
}

// P_part = x[bt, krange]^T @ Y[bt, krange] (64x64) + partial colsum(Y)
__global__ __launch_bounds__(256) void k_pmat(
    const float* __restrict__ X, const float* __restrict__ Y,
    float* __restrict__ P, float* __restrict__ CS)
{
  __shared__ float Xs[CC][68];  // natural [k][c]
  __shared__ float Ys[CC][68];
  const int tid = threadIdx.x;
  const int ty = tid >> 4, tx = tid & 15;
  const int part = blockIdx.x, bt = blockIdx.y;
  float acc[4][4] = {};
  float csacc = 0.f;
  for (int kk = part * 128; kk < part * 128 + 128; kk += 64) {
#pragma unroll
    for (int j = 0; j < 4; ++j) {
      int idx = tid + 256 * j;
      int r = idx >> 4, c4 = idx & 15;
      *(float4*)&Xs[r][c4 * 4] =
          *(const float4*)(X + ((size_t)bt * NN + kk + r) * CC + c4 * 4);
      *(float4*)&Ys[r][c4 * 4] =
          *(const float4*)(Y + ((size_t)bt * NN + kk + r) * CC + c4 * 4);
    }
    __syncthreads();
    for (int k = 0; k < 64; ++k)
      fma16(acc, *(const float4*)&Xs[k][ty * 4], *(const float4*)&Ys[k][tx * 4]);
    if (tid < 64) {
      float s = 0.f;
      for (int k = 0; k < 64; ++k) s += Ys[k][tid];
      csacc += s;
    }
    __syncthreads();
  }
  float* Pb = P + ((size_t)bt * 4 + part) * CC * CC;
#pragma unroll
  for (int i = 0; i < 4; ++i) {
    float4 o = {acc[i][0], acc[i][1], acc[i][2], acc[i][3]};
    *(float4*)(Pb + (size_t)(ty * 4 + i) * CC + tx * 4) = o;
  }
  if (tid < 64) CS[((size_t)bt * 4 + part) * CC + tid] = csacc;
}

// Y = alpha*( s*(H@Psum) + c*colsum ) + beta*R ; store Y; Out += Y @ W
__global__ __launch_bounds__(256) void k_cheb(
    const float* __restrict__ Hbuf, const float* __restrict__ P,
    const float* __restrict__ CS, const float* __restrict__ sc,
    const float* __restrict__ R, const float* __restrict__ W,
    float alpha, float beta,
    float* __restrict__ Yout, float* __restrict__ Out)
{
  __shared__ float As[CC][68];  // H tile transposed
  __shared__ float Ps[CC][68];  // summed P, natural
  __shared__ float Ts[CC][68];
  __shared__ float csl[CC];
  const int tid = threadIdx.x;
  const int ty = tid >> 4, tx = tid & 15;
  const int bt = blockIdx.y;
  const int i0 = blockIdx.x * 64;
  const float* Hb = Hbuf + ((size_t)bt * NN + i0) * CC;
  const float* Pb = P + (size_t)bt * 4 * CC * CC;
#pragma unroll
  for (int j = 0; j < 4; ++j) {
    int idx = tid + 256 * j;
    int r = idx >> 4, c4 = idx & 15;
    float4 v = *(const float4*)(Hb + (size_t)r * CC + c4 * 4);
    As[c4 * 4 + 0][r] = v.x; As[c4 * 4 + 1][r] = v.y;
    As[c4 * 4 + 2][r] = v.z; As[c4 * 4 + 3][r] = v.w;
    float4 p0 = *(const float4*)(Pb + idx * 4);
    float4 p1 = *(const float4*)(Pb + CC * CC + idx * 4);
    float4 p2 = *(const float4*)(Pb + 2 * CC * CC + idx * 4);
    float4 p3 = *(const float4*)(Pb + 3 * CC * CC + idx * 4);
    float4 ps = {p0.x + p1.x + p2.x + p3.x, p0.y + p1.y + p2.y + p3.y,
                 p0.z + p1.z + p2.z + p3.z, p0.w + p1.w + p2.w + p3.w};
    *(float4*)&Ps[r][c4 * 4] = ps;
  }
  if (tid < CC) {
    const float* cb = CS + (size_t)bt * 4 * CC;
    csl[tid] = cb[tid] + cb[CC + tid] + cb[2 * CC + tid] + cb[3 * CC + tid];
  }
  __syncthreads();
  float acc[4][4] = {};
  for (int k = 0; k < CC; ++k)
    fma16(acc, *(const float4*)&As[k][ty * 4], *(const float4*)&Ps[k][tx * 4]);
  const float s = sc[0], csh = sc[1];
  const size_t obase = ((size_t)bt * NN + i0) * CC;
  float tv[4][4];
  if (R) {
#pragma unroll
    for (int i = 0; i < 4; ++i) {
      float4 rv = *(const float4*)(R + obase + (size_t)(ty * 4 + i) * CC + tx * 4);
      const float rr[4] = {rv.x, rv.y, rv.z, rv.w};
#pragma unroll
      for (int j = 0; j < 4; ++j)
        tv[i][j] = alpha * (s * acc[i][j] + csh * csl[tx * 4 + j]) + beta * rr[j];
    }
  } else {
#pragma unroll
    for (int i = 0; i < 4; ++i)
#pragma unroll
      for (int j = 0; j < 4; ++j)
        tv[i][j] = alpha * (s * acc[i][j] + csh * csl[tx * 4 + j]);
  }
  epilogue_store_acc(tv, W, Ts, As, Yout, Out, obase, ty, tx, tid);
}

extern "C" void kernel_launch(void* const* d_in, const int* in_sizes, int n_in,
                              void* d_out, int out_size, void* d_ws, size_t ws_size,
                              hipStream_t stream)
{
  (void)in_sizes; (void)n_in; (void)out_size; (void)ws_size;
  const float* x   = (const float*)d_in[0];  // (4,12,512,64)
  const float* wsL = (const float*)d_in[1];  // (512,512)
  const float* ts  = (const float*)d_in[2];  // (3,64,64)
  const float* wp  = (const float*)d_in[3];  // (64,64)
  const float* td  = (const float*)d_in[4];  // (6,64,64)
  float* out = (float*)d_out;
  float* wsf = (float*)d_ws;
  float* H  = wsf + OFF_H;
  float* Y1 = wsf + OFF_Y1;
  float* Ya = wsf + OFF_YA;
  float* Yb = wsf + OFF_YB;
  float* P  = wsf + OFF_P;
  float* CS = wsf + OFF_CS;
  const float* ts0 = ts;          const float* ts1 = ts + 4096;
  const float* ts2 = ts + 8192;
  const float* td0 = td;          const float* td1 = td + 4096;
  const float* td2 = td + 8192;   const float* td3 = td + 12288;
  const float* td4 = td + 16384;  const float* td5 = td + 20480;

  dim3 g8(8, BT), g88(8, 8, BT), g4(4, BT);

  // H = x @ wp  (per bt)
  k_small_mm<<<g8, 256, 0, stream>>>(x, wp, nullptr, H);
  // global min/max of wd_raw = H @ x^T
  k_minmax<<<g88, 256, 0, stream>>>(H, x, wsf);
  k_reduce<<<1, 256, 0, stream>>>(wsf);
  // out = x @ (ts0 + td0)   (initializes d_out)
  k_small_mm<<<g8, 256, 0, stream>>>(x, ts0, td0, out);
  // static branch: Z1 = ws@x ; out += Z1@ts1 ; Z2 = 2 ws@Z1 - x ; out += Z2@ts2
  k_bigmm<<<g8, 256, 0, stream>>>(wsL, x,  nullptr, ts1, 1.f,  0.f, Ya, out);
  k_bigmm<<<g8, 256, 0, stream>>>(wsL, Ya, x,       ts2, 2.f, -1.f, Yb, out);
  // dynamic branch: Y1 = wd@x ; Y2 = 2wd@Y1 - x ; Y_{i+1} = 2wd@Y_i - Y1
  k_pmat<<<g4, 256, 0, stream>>>(x, x, P, CS);
  k_cheb<<<g8, 256, 0, stream>>>(H, P, CS, wsf, nullptr, td1, 1.f,  0.f, Y1, out);
  k_pmat<<<g4, 256, 0, stream>>>(x, Y1, P, CS);
  k_cheb<<<g8, 256, 0, stream>>>(H, P, CS, wsf, x,  td2, 2.f, -1.f, Ya, out);
  k_pmat<<<g4, 256, 0, stream>>>(x, Ya, P, CS);
  k_cheb<<<g8, 256, 0, stream>>>(H, P, CS, wsf, Y1, td3, 2.f, -1.f, Yb, out);
  k_pmat<<<g4, 256, 0, stream>>>(x, Yb, P, CS);
  k_cheb<<<g8, 256, 0, stream>>>(H, P, CS, wsf, Y1, td4, 2.f, -1.f, Ya, out);
  k_pmat<<<g4, 256, 0, stream>>>(x, Ya, P, CS);
  k_cheb<<<g8, 256, 0, stream>>>(H, P, CS, wsf, Y1, td5, 2.f, -1.f, Yb, out);
}

// Round 3
// 121.436 us; speedup vs baseline: 2.1135x; 2.1135x over previous
//
#include <hip/hip_runtime.h>
#include <cstddef>
#include <cstdint>

#define NN 512
#define CC 64
#define BT 48

typedef __bf16 bf16_t;
typedef bf16_t bf16x8 __attribute__((ext_vector_type(8)));
typedef bf16_t bf16x4 __attribute__((ext_vector_type(4)));
typedef float f32x4 __attribute__((ext_vector_type(4)));

// ---- workspace word offsets (float words) ----
#define OFF_SC    0          // s, c
#define OFF_MN    16         // 3072 block-min
#define OFF_MX    3088       // 3072 block-max
#define OFF_WSB   8192       // ws bf16 natural [512][512]
#define OFF_XBT   139264     // x^T bf16 [48][64][512]
#define OFF_XRT   925696     // residual of x^T bf16
#define OFF_HB    1712128    // H bf16 natural [48][512][64]
#define OFF_HR    2498560    // H residual bf16
#define OFF_WTS   3284992    // 8 transposed weights bf16 [8][64][64]
#define OFF_Z1T   3301376
#define OFF_Z2T   4087808
#define OFF_Y1T   4874240
#define OFF_Y2T   5660672
#define OFF_Y3T   6447104
#define OFF_Y4T   7233536
#define OFF_Y5T   8019968
#define OFF_PTP0  8806400    // PT partials bf16 [48][8][64][64]
#define OFF_PTP1  9592832
#define OFF_CSP0  10379264   // colsum partials f32 [48][8][64]
#define OFF_CSP1  10403840

__device__ __forceinline__ f32x4 mfma(bf16x8 a, bf16x8 b, f32x4 c) {
  return __builtin_amdgcn_mfma_f32_16x16x32_bf16(a, b, c, 0, 0, 0);
}
// element offset of 8-elem chunk (r, c8) in swizzled 64x64 bf16 tile
__device__ __forceinline__ int swz_chunk(int r, int c8) {
  return r * 64 + ((c8 ^ (r & 7)) << 3);
}
// element offset of single element (r, c)
__device__ __forceinline__ int swz_e(int r, int c) {
  return r * 64 + ((((c >> 3) ^ (r & 7)) << 3)) + (c & 7);
}
__device__ __forceinline__ bf16x8 frag(const bf16_t* sm, int row, int kc) {
  return *(const bf16x8*)(sm + row * 64 + ((kc ^ (row & 7)) << 3));
}
// stage 64x64 bf16 tile from global (row stride ld elems) into swizzled LDS
__device__ __forceinline__ void stage64(bf16_t* sm, const bf16_t* g, int ld, int tid) {
#pragma unroll
  for (int j = 0; j < 2; ++j) {
    int id = tid + 256 * j;
    int r = id >> 3, c8 = id & 7;
    bf16x8 v = *(const bf16x8*)(g + (size_t)r * ld + c8 * 8);
    *(bf16x8*)(sm + swz_chunk(r, c8)) = v;
  }
}
struct bfpair { bf16_t b, r; };
__device__ __forceinline__ bfpair splitbf(float f) {
  bfpair p;
  p.b = (bf16_t)f;
  p.r = (bf16_t)(f - (float)p.b);
  return p;
}

// ============ prep: conversions, H (split MFMA), PT0/cs0 partials, wsb, WTs ============
__global__ __launch_bounds__(256) void k_prep(
    const float* __restrict__ x, const float* __restrict__ wsL,
    const float* __restrict__ ts, const float* __restrict__ wp,
    const float* __restrict__ td, float* __restrict__ wsf)
{
  __shared__ __align__(16) float XsF[64][65];
  __shared__ __align__(16) bf16_t Ab[64*64], Ar[64*64], Tb[64*64], Wb[64*64], Wr[64*64];
  const int tid = threadIdx.x;
  const int bx = blockIdx.x, by = blockIdx.y;
  bf16_t* WSB = (bf16_t*)(wsf + OFF_WSB);
  bf16_t* WTS = (bf16_t*)(wsf + OFF_WTS);
  if (by == 48) {
    // convert ws slice rows [bx*64, bx*64+64)
    const float* wrow = wsL + (size_t)bx * 64 * 512;
    bf16_t* wob = WSB + (size_t)bx * 64 * 512;
    for (int j = 0; j < 32; ++j) {
      int idx = tid + 256 * j;  // float4 groups, 8192 total
      float4 v = *(const float4*)(wrow + (size_t)idx * 4);
      bf16x4 o = {(bf16_t)v.x, (bf16_t)v.y, (bf16_t)v.z, (bf16_t)v.w};
      *(bf16x4*)(wob + (size_t)idx * 4) = o;
    }
    if (bx == 0) {
      // transposed weights: 0->ts0+td0, 1->ts1, 2->ts2, 3..7->td1..td5
      for (int m = 0; m < 8; ++m) {
        const float* s1; const float* s2 = nullptr;
        if (m == 0)      { s1 = ts;               s2 = td; }
        else if (m <= 2) { s1 = ts + m * 4096; }
        else             { s1 = td + (m - 2) * 4096; }
        __syncthreads();
        for (int j = 0; j < 4; ++j) {
          int idx = tid + 256 * j;
          int r = idx >> 4, c0 = (idx & 15) * 4;
          float4 v = *(const float4*)(s1 + r * 64 + c0);
          if (s2) { float4 u = *(const float4*)(s2 + r * 64 + c0);
                    v.x += u.x; v.y += u.y; v.z += u.z; v.w += u.w; }
          XsF[c0 + 0][r] = v.x; XsF[c0 + 1][r] = v.y;
          XsF[c0 + 2][r] = v.z; XsF[c0 + 3][r] = v.w;
        }
        __syncthreads();
        bf16_t* wt = WTS + m * 4096;
        for (int j = 0; j < 2; ++j) {
          int id = tid + 256 * j;
          int r = id >> 3, c8 = (id & 7) * 8;
          bf16x8 o;
#pragma unroll
          for (int q = 0; q < 8; ++q) o[q] = (bf16_t)XsF[r][c8 + q];
          *(bf16x8*)(wt + r * 64 + c8) = o;
        }
      }
    }
    return;
  }
  const int bt = by, i0 = bx * 64;
  bf16_t* XBT = (bf16_t*)(wsf + OFF_XBT);
  bf16_t* XRT = (bf16_t*)(wsf + OFF_XRT);
  bf16_t* HBp = (bf16_t*)(wsf + OFF_HB);
  bf16_t* HRp = (bf16_t*)(wsf + OFF_HR);
  bf16_t* PT0 = (bf16_t*)(wsf + OFF_PTP0);
  float*  CS0 = wsf + OFF_CSP0;
  const float* xg = x + ((size_t)bt * NN + i0) * CC;
  // stage x tile: natural bf16+res (Ab/Ar), fp32 transpose (XsF), bf16 transpose (Tb)
  for (int j = 0; j < 4; ++j) {
    int idx = tid + 256 * j;
    int r = idx >> 4, c0 = (idx & 15) * 4;
    float4 v = *(const float4*)(xg + (size_t)r * CC + c0);
    bfpair p0 = splitbf(v.x), p1 = splitbf(v.y), p2 = splitbf(v.z), p3 = splitbf(v.w);
    bf16x4 vb = {p0.b, p1.b, p2.b, p3.b};
    bf16x4 vr = {p0.r, p1.r, p2.r, p3.r};
    *(bf16x4*)(Ab + swz_e(r, c0)) = vb;
    *(bf16x4*)(Ar + swz_e(r, c0)) = vr;
    XsF[c0 + 0][r] = v.x; XsF[c0 + 1][r] = v.y;
    XsF[c0 + 2][r] = v.z; XsF[c0 + 3][r] = v.w;
    Tb[swz_e(c0 + 0, r)] = p0.b; Tb[swz_e(c0 + 1, r)] = p1.b;
    Tb[swz_e(c0 + 2, r)] = p2.b; Tb[swz_e(c0 + 3, r)] = p3.b;
  }
  // wp split, transposed into Wb/Wr [cout][cin]
  for (int j = 0; j < 4; ++j) {
    int idx = tid + 256 * j;
    int r = idx >> 4, c0 = (idx & 15) * 4;   // r = cin
    float4 v = *(const float4*)(wp + r * 64 + c0);
    bfpair p0 = splitbf(v.x), p1 = splitbf(v.y), p2 = splitbf(v.z), p3 = splitbf(v.w);
    Wb[swz_e(c0 + 0, r)] = p0.b; Wr[swz_e(c0 + 0, r)] = p0.r;
    Wb[swz_e(c0 + 1, r)] = p1.b; Wr[swz_e(c0 + 1, r)] = p1.r;
    Wb[swz_e(c0 + 2, r)] = p2.b; Wr[swz_e(c0 + 2, r)] = p2.r;
    Wb[swz_e(c0 + 3, r)] = p3.b; Wr[swz_e(c0 + 3, r)] = p3.r;
  }
  __syncthreads();
  // global writes of x^T (bf16 + residual) from XsF rows
  {
    int c = tid >> 2, k0 = (tid & 3) * 16;
    bf16x8 o1, o2, q1, q2;
#pragma unroll
    for (int q = 0; q < 8; ++q) {
      bfpair a = splitbf(XsF[c][k0 + q]);
      bfpair b = splitbf(XsF[c][k0 + 8 + q]);
      o1[q] = a.b; q1[q] = a.r;
      o2[q] = b.b; q2[q] = b.r;
    }
    size_t base = ((size_t)bt * 64 + c) * 512 + i0 + k0;
    *(bf16x8*)(XBT + base) = o1; *(bf16x8*)(XBT + base + 8) = o2;
    *(bf16x8*)(XRT + base) = q1; *(bf16x8*)(XRT + base + 8) = q2;
  }
  if (tid < 64) {  // colsum(x) partial over this n-slice
    float s = 0.f;
    for (int r = 0; r < 64; ++r) s += XsF[tid][r];
    CS0[((size_t)bt * 8 + bx) * 64 + tid] = s;
  }
  // MFMA: H = x@wp (split, 3 products) and PT0 partial = xT @ x
  const int w = tid >> 6, l = tid & 63, lh = l >> 4, lr = l & 15, m0 = w * 16;
  f32x4 accH[4] = {}; f32x4 accP[4] = {};
#pragma unroll
  for (int q = 0; q < 2; ++q) {
    bf16x8 ab = frag(Ab, m0 + lr, q * 4 + lh);
    bf16x8 ar = frag(Ar, m0 + lr, q * 4 + lh);
    bf16x8 at = frag(Tb, m0 + lr, q * 4 + lh);
#pragma unroll
    for (int t = 0; t < 4; ++t) {
      bf16x8 bb = frag(Wb, t * 16 + lr, q * 4 + lh);
      bf16x8 br = frag(Wr, t * 16 + lr, q * 4 + lh);
      accH[t] = mfma(ab, bb, accH[t]);
      accH[t] = mfma(ab, br, accH[t]);
      accH[t] = mfma(ar, bb, accH[t]);
      bf16x8 bt_ = frag(Tb, t * 16 + lr, q * 4 + lh);
      accP[t] = mfma(at, bt_, accP[t]);
    }
  }
  // PT0 partial (bf16)
  {
    bf16_t* po = PT0 + ((size_t)bt * 8 + bx) * 4096;
#pragma unroll
    for (int t = 0; t < 4; ++t)
#pragma unroll
      for (int r = 0; r < 4; ++r)
        po[(m0 + 4 * lh + r) * 64 + t * 16 + lr] = (bf16_t)accP[t][r];
  }
  __syncthreads();
  // scatter H (fp32) into XsF as [n][c]
#pragma unroll
  for (int t = 0; t < 4; ++t)
#pragma unroll
    for (int r = 0; r < 4; ++r)
      XsF[m0 + 4 * lh + r][t * 16 + lr] = accH[t][r];
  __syncthreads();
  // write Hb/Hr natural
  {
    int r = tid >> 2, c0 = (tid & 3) * 16;
    bf16x8 o1, o2, q1, q2;
#pragma unroll
    for (int q = 0; q < 8; ++q) {
      bfpair a = splitbf(XsF[r][c0 + q]);
      bfpair b = splitbf(XsF[r][c0 + 8 + q]);
      o1[q] = a.b; q1[q] = a.r;
      o2[q] = b.b; q2[q] = b.r;
    }
    size_t base = ((size_t)bt * 512 + i0 + r) * 64 + c0;
    *(bf16x8*)(HBp + base) = o1; *(bf16x8*)(HBp + base + 8) = o2;
    *(bf16x8*)(HRp + base) = q1; *(bf16x8*)(HRp + base + 8) = q2;
  }
}

// ============ minmax of wd_raw = H @ x^T (split bf16, 3 products) ============
__global__ __launch_bounds__(256) void k_minmax(const float* __restrict__ x,
                                                float* __restrict__ wsf)
{
  __shared__ __align__(16) bf16_t Ha[64*64], Hc[64*64], Xa[64*64], Xc[64*64];
  __shared__ float red[16];
  const int tid = threadIdx.x;
  const int bx = blockIdx.x, byj = blockIdx.y, bt = blockIdx.z;
  const bf16_t* HBp = (const bf16_t*)(wsf + OFF_HB);
  const bf16_t* HRp = (const bf16_t*)(wsf + OFF_HR);
  stage64(Ha, HBp + ((size_t)bt * 512 + bx * 64) * 64, 64, tid);
  stage64(Hc, HRp + ((size_t)bt * 512 + bx * 64) * 64, 64, tid);
  const float* xg = x + ((size_t)bt * NN + byj * 64) * CC;
  for (int j = 0; j < 4; ++j) {
    int idx = tid + 256 * j;
    int r = idx >> 4, c0 = (idx & 15) * 4;
    float4 v = *(const float4*)(xg + (size_t)r * CC + c0);
    bfpair p0 = splitbf(v.x), p1 = splitbf(v.y), p2 = splitbf(v.z), p3 = splitbf(v.w);
    bf16x4 vb = {p0.b, p1.b, p2.b, p3.b};
    bf16x4 vr = {p0.r, p1.r, p2.r, p3.r};
    *(bf16x4*)(Xa + swz_e(r, c0)) = vb;
    *(bf16x4*)(Xc + swz_e(r, c0)) = vr;
  }
  __syncthreads();
  const int w = tid >> 6, l = tid & 63, lh = l >> 4, lr = l & 15, m0 = w * 16;
  f32x4 acc[4] = {};
#pragma unroll
  for (int q = 0; q < 2; ++q) {
    bf16x8 ab = frag(Ha, m0 + lr, q * 4 + lh);
    bf16x8 ar = frag(Hc, m0 + lr, q * 4 + lh);
#pragma unroll
    for (int t = 0; t < 4; ++t) {
      bf16x8 bb = frag(Xa, t * 16 + lr, q * 4 + lh);
      bf16x8 br = frag(Xc, t * 16 + lr, q * 4 + lh);
      acc[t] = mfma(ab, bb, acc[t]);
      acc[t] = mfma(ab, br, acc[t]);
      acc[t] = mfma(ar, bb, acc[t]);
    }
  }
  float mn = acc[0][0], mx = acc[0][0];
#pragma unroll
  for (int t = 0; t < 4; ++t)
#pragma unroll
    for (int r = 0; r < 4; ++r) { mn = fminf(mn, acc[t][r]); mx = fmaxf(mx, acc[t][r]); }
  for (int off = 32; off; off >>= 1) {
    mn = fminf(mn, __shfl_xor(mn, off));
    mx = fmaxf(mx, __shfl_xor(mx, off));
  }
  if (l == 0) { red[w] = mn; red[8 + w] = mx; }
  __syncthreads();
  if (tid == 0) {
    mn = fminf(fminf(red[0], red[1]), fminf(red[2], red[3]));
    mx = fmaxf(fmaxf(red[8], red[9]), fmaxf(red[10], red[11]));
    int id = (bt * 8 + byj) * 8 + bx;
    wsf[OFF_MN + id] = mn; wsf[OFF_MX + id] = mx;
  }
}

__global__ __launch_bounds__(256) void k_reduce(float* __restrict__ wsf)
{
  const int tid = threadIdx.x;
  float mn = 3.4e38f, mx = -3.4e38f;
  for (int i = tid; i < 3072; i += 256) {
    mn = fminf(mn, wsf[OFF_MN + i]);
    mx = fmaxf(mx, wsf[OFF_MX + i]);
  }
  for (int off = 32; off; off >>= 1) {
    mn = fminf(mn, __shfl_xor(mn, off));
    mx = fmaxf(mx, __shfl_xor(mx, off));
  }
  __shared__ float red[16];
  if ((tid & 63) == 0) { red[tid >> 6] = mn; red[8 + (tid >> 6)] = mx; }
  __syncthreads();
  if (tid == 0) {
    mn = fminf(fminf(red[0], red[1]), fminf(red[2], red[3]));
    mx = fmaxf(fmaxf(red[8], red[9]), fmaxf(red[10], red[11]));
    float s = 1.0f / (mx + mn) / 262144.0f;
    wsf[0] = s;
    wsf[1] = mn * s;
  }
}

// ============ big static matmul: OT = alpha*(AT @ ws^T) [- (Rb+Rr)] ============
__global__ __launch_bounds__(256) void k_bigmm(
    const bf16_t* __restrict__ AT, const bf16_t* __restrict__ WSB,
    const bf16_t* __restrict__ Rb, const bf16_t* __restrict__ Rr,
    float alpha, bf16_t* __restrict__ OT)
{
  __shared__ __align__(16) bf16_t As[64*64], Bs[64*64], Ys[64*64];
  const int tid = threadIdx.x;
  const int bx = blockIdx.x, bt = blockIdx.y;
  const bf16_t* Ag = AT + (size_t)bt * 64 * 512;
  const bf16_t* Bg = WSB + (size_t)bx * 64 * 512;
  const int w = tid >> 6, l = tid & 63, lh = l >> 4, lr = l & 15, m0 = w * 16;
  f32x4 acc[4] = {};
  for (int kk = 0; kk < 8; ++kk) {
    if (kk) __syncthreads();
#pragma unroll
    for (int j = 0; j < 2; ++j) {
      int id = tid + 256 * j;
      int r = id >> 3, c8 = id & 7;
      *(bf16x8*)(As + swz_chunk(r, c8)) =
          *(const bf16x8*)(Ag + (size_t)r * 512 + kk * 64 + c8 * 8);
      *(bf16x8*)(Bs + swz_chunk(r, c8)) =
          *(const bf16x8*)(Bg + (size_t)r * 512 + kk * 64 + c8 * 8);
    }
    __syncthreads();
#pragma unroll
    for (int q = 0; q < 2; ++q) {
      bf16x8 a = frag(As, m0 + lr, q * 4 + lh);
#pragma unroll
      for (int t = 0; t < 4; ++t)
        acc[t] = mfma(a, frag(Bs, t * 16 + lr, q * 4 + lh), acc[t]);
    }
  }
#pragma unroll
  for (int t = 0; t < 4; ++t)
#pragma unroll
    for (int r = 0; r < 4; ++r) {
      int cy = m0 + 4 * lh + r, nl = t * 16 + lr;
      float v = alpha * acc[t][r];
      if (Rb) {
        size_t off = ((size_t)bt * 64 + cy) * 512 + bx * 64 + nl;
        float rv = (float)Rb[off] + (float)Rr[off];
        v -= rv;
      }
      Ys[swz_e(cy, nl)] = (bf16_t)v;
    }
  __syncthreads();
#pragma unroll
  for (int j = 0; j < 2; ++j) {
    int id = tid + 256 * j;
    int r = id >> 3, c8 = id & 7;
    *(bf16x8*)(OT + ((size_t)bt * 64 + r) * 512 + bx * 64 + c8 * 8) =
        *(const bf16x8*)(Ys + swz_chunk(r, c8));
  }
}

// ============ dynamic Chebyshev step ============
// YT = alpha*(s*(PTsum @ H^T) + c*cs) [- R1 (+R2)] ; PTout partial, CSout partial
__global__ __launch_bounds__(256) void k_cheb(
    const bf16_t* __restrict__ PTin, const float* __restrict__ CSin,
    const bf16_t* __restrict__ HBg, const float* __restrict__ wsf,
    const bf16_t* __restrict__ R1, const bf16_t* __restrict__ R2, float alpha,
    const bf16_t* __restrict__ XBTg, bf16_t* __restrict__ YTout,
    bf16_t* __restrict__ PTout, float* __restrict__ CSout)
{
  __shared__ __align__(16) bf16_t Aps[64*64], Bhs[64*64], Yts[64*64], Bxs[64*64];
  __shared__ float csl[64];
  const int tid = threadIdx.x;
  const int bx = blockIdx.x, bt = blockIdx.y;
  // A = sum of 8 PT partials -> bf16 swizzled
  const bf16_t* pb = PTin + (size_t)bt * 8 * 4096;
  for (int j = 0; j < 4; ++j) {
    int idx = tid + 256 * j;
    int cy = idx >> 4, c0 = (idx & 15) * 4;
    float s0 = 0, s1 = 0, s2 = 0, s3 = 0;
#pragma unroll
    for (int k = 0; k < 8; ++k) {
      bf16x4 v = *(const bf16x4*)(pb + k * 4096 + cy * 64 + c0);
      s0 += (float)v[0]; s1 += (float)v[1]; s2 += (float)v[2]; s3 += (float)v[3];
    }
    bf16x4 o = {(bf16_t)s0, (bf16_t)s1, (bf16_t)s2, (bf16_t)s3};
    *(bf16x4*)(Aps + swz_e(cy, c0)) = o;
  }
  if (tid < 64) {
    const float* cb = CSin + (size_t)bt * 8 * 64;
    float s = 0.f;
#pragma unroll
    for (int k = 0; k < 8; ++k) s += cb[k * 64 + tid];
    csl[tid] = s;
  }
  stage64(Bhs, HBg + ((size_t)bt * 512 + bx * 64) * 64, 64, tid);
  __syncthreads();
  const int w = tid >> 6, l = tid & 63, lh = l >> 4, lr = l & 15, m0 = w * 16;
  f32x4 acc[4] = {};
#pragma unroll
  for (int q = 0; q < 2; ++q) {
    bf16x8 a = frag(Aps, m0 + lr, q * 4 + lh);
#pragma unroll
    for (int t = 0; t < 4; ++t)
      acc[t] = mfma(a, frag(Bhs, t * 16 + lr, q * 4 + lh), acc[t]);
  }
  const float sS = wsf[0], sC = wsf[1];
  float tv[4][4];
#pragma unroll
  for (int t = 0; t < 4; ++t)
#pragma unroll
    for (int r = 0; r < 4; ++r) {
      int cy = m0 + 4 * lh + r, nl = t * 16 + lr;
      float v = alpha * (sS * acc[t][r] + sC * csl[cy]);
      if (R1) {
        size_t off = ((size_t)bt * 64 + cy) * 512 + bx * 64 + nl;
        float rv = (float)R1[off];
        if (R2) rv += (float)R2[off];
        v -= rv;
      }
      tv[t][r] = v;
    }
  if (CSout) {  // colsum partial over this n-slice via in-lane + 16-lane reduce
#pragma unroll
    for (int r = 0; r < 4; ++r) {
      float v = tv[0][r] + tv[1][r] + tv[2][r] + tv[3][r];
      v += __shfl_xor(v, 1); v += __shfl_xor(v, 2);
      v += __shfl_xor(v, 4); v += __shfl_xor(v, 8);
      if (lr == 0) CSout[((size_t)bt * 8 + bx) * 64 + m0 + 4 * lh + r] = v;
    }
  }
#pragma unroll
  for (int t = 0; t < 4; ++t)
#pragma unroll
    for (int r = 0; r < 4; ++r)
      Yts[swz_e(m0 + 4 * lh + r, t * 16 + lr)] = (bf16_t)tv[t][r];
  if (PTout) {
#pragma unroll
    for (int j = 0; j < 2; ++j) {
      int id = tid + 256 * j;
      int r = id >> 3, c8 = id & 7;
      *(bf16x8*)(Bxs + swz_chunk(r, c8)) =
          *(const bf16x8*)(XBTg + ((size_t)bt * 64 + r) * 512 + bx * 64 + c8 * 8);
    }
  }
  __syncthreads();
#pragma unroll
  for (int j = 0; j < 2; ++j) {
    int id = tid + 256 * j;
    int r = id >> 3, c8 = id & 7;
    *(bf16x8*)(YTout + ((size_t)bt * 64 + r) * 512 + bx * 64 + c8 * 8) =
        *(const bf16x8*)(Yts + swz_chunk(r, c8));
  }
  if (PTout) {
    f32x4 ap[4] = {};
#pragma unroll
    for (int q = 0; q < 2; ++q) {
      bf16x8 a = frag(Yts, m0 + lr, q * 4 + lh);
#pragma unroll
      for (int t = 0; t < 4; ++t)
        ap[t] = mfma(a, frag(Bxs, t * 16 + lr, q * 4 + lh), ap[t]);
    }
    bf16_t* po = PTout + ((size_t)bt * 8 + bx) * 4096;
#pragma unroll
    for (int t = 0; t < 4; ++t)
#pragma unroll
      for (int r = 0; r < 4; ++r)
        po[(m0 + 4 * lh + r) * 64 + t * 16 + lr] = (bf16_t)ap[t][r];
  }
}

// ============ final: Out = sum of 8 terms [n][cin] @ W[cin][cout], K=512 ============
__global__ __launch_bounds__(256) void k_out(
    const bf16_t* __restrict__ T0, const bf16_t* __restrict__ T1,
    const bf16_t* __restrict__ T2, const bf16_t* __restrict__ T3,
    const bf16_t* __restrict__ T4, const bf16_t* __restrict__ T5,
    const bf16_t* __restrict__ T6, const bf16_t* __restrict__ T7,
    const bf16_t* __restrict__ WTSg, float* __restrict__ out)
{
  __shared__ __align__(16) bf16_t As[64*64], Bs[64*64];
  const int tid = threadIdx.x;
  const int bx = blockIdx.x, bt = blockIdx.y;
  const bf16_t* terms[8] = {T0, T1, T2, T3, T4, T5, T6, T7};
  const int w = tid >> 6, l = tid & 63, lh = l >> 4, lr = l & 15, m0 = w * 16;
  f32x4 acc[4] = {};
#pragma unroll
  for (int m = 0; m < 8; ++m) {
    if (m) __syncthreads();
    // A: transpose-stage term [bt][c][i0+n] -> As[n][c]
#pragma unroll
    for (int j = 0; j < 2; ++j) {
      int id = tid + 256 * j;
      int cr = id >> 3, n8 = (id & 7) * 8;
      bf16x8 v = *(const bf16x8*)(terms[m] + ((size_t)bt * 64 + cr) * 512 + bx * 64 + n8);
#pragma unroll
      for (int q = 0; q < 8; ++q)
        As[swz_e(n8 + q, cr)] = v[q];
    }
#pragma unroll
    for (int j = 0; j < 2; ++j) {
      int id = tid + 256 * j;
      int r = id >> 3, c8 = id & 7;
      *(bf16x8*)(Bs + swz_chunk(r, c8)) =
          *(const bf16x8*)(WTSg + m * 4096 + (size_t)r * 64 + c8 * 8);
    }
    __syncthreads();
#pragma unroll
    for (int q = 0; q < 2; ++q) {
      bf16x8 a = frag(As, m0 + lr, q * 4 + lh);
#pragma unroll
      for (int t = 0; t < 4; ++t)
        acc[t] = mfma(a, frag(Bs, t * 16 + lr, q * 4 + lh), acc[t]);
    }
  }
  float* ob = out + ((size_t)bt * NN + bx * 64) * CC;
#pragma unroll
  for (int t = 0; t < 4; ++t)
#pragma unroll
    for (int r = 0; r < 4; ++r)
      ob[(size_t)(m0 + 4 * lh + r) * CC + t * 16 + lr] = acc[t][r];
}

extern "C" void kernel_launch(void* const* d_in, const int* in_sizes, int n_in,
                              void* d_out, int out_size, void* d_ws, size_t ws_size,
                              hipStream_t stream)
{
  (void)in_sizes; (void)n_in; (void)out_size; (void)ws_size;
  const float* x   = (const float*)d_in[0];
  const float* wsL = (const float*)d_in[1];
  const float* ts  = (const float*)d_in[2];
  const float* wp  = (const float*)d_in[3];
  const float* td  = (const float*)d_in[4];
  float* out = (float*)d_out;
  float* wsf = (float*)d_ws;
  bf16_t* WSB = (bf16_t*)(wsf + OFF_WSB);
  bf16_t* XBT = (bf16_t*)(wsf + OFF_XBT);
  bf16_t* XRT = (bf16_t*)(wsf + OFF_XRT);
  bf16_t* HB  = (bf16_t*)(wsf + OFF_HB);
  bf16_t* WTS = (bf16_t*)(wsf + OFF_WTS);
  bf16_t* Z1T = (bf16_t*)(wsf + OFF_Z1T);
  bf16_t* Z2T = (bf16_t*)(wsf + OFF_Z2T);
  bf16_t* Y1T = (bf16_t*)(wsf + OFF_Y1T);
  bf16_t* Y2T = (bf16_t*)(wsf + OFF_Y2T);
  bf16_t* Y3T = (bf16_t*)(wsf + OFF_Y3T);
  bf16_t* Y4T = (bf16_t*)(wsf + OFF_Y4T);
  bf16_t* Y5T = (bf16_t*)(wsf + OFF_Y5T);
  bf16_t* PTP0 = (bf16_t*)(wsf + OFF_PTP0);
  bf16_t* PTP1 = (bf16_t*)(wsf + OFF_PTP1);
  float* CSP0 = wsf + OFF_CSP0;
  float* CSP1 = wsf + OFF_CSP1;
  dim3 b(256);

  k_prep  <<<dim3(8, 49),   b, 0, stream>>>(x, wsL, ts, wp, td, wsf);
  k_minmax<<<dim3(8, 8, 48), b, 0, stream>>>(x, wsf);
  k_reduce<<<1,              b, 0, stream>>>(wsf);
  // static branch: Z1^T = x^T @ ws^T ; Z2^T = 2*Z1^T @ ws^T - x^T
  k_bigmm <<<dim3(8, 48), b, 0, stream>>>(XBT, WSB, nullptr, nullptr, 1.f, Z1T);
  k_bigmm <<<dim3(8, 48), b, 0, stream>>>(Z1T, WSB, XBT, XRT, 2.f, Z2T);
  // dynamic branch
  k_cheb<<<dim3(8, 48), b, 0, stream>>>(PTP0, CSP0, HB, wsf, nullptr, nullptr, 1.f, XBT, Y1T, PTP1, CSP1);
  k_cheb<<<dim3(8, 48), b, 0, stream>>>(PTP1, CSP1, HB, wsf, XBT, XRT,   2.f, XBT, Y2T, PTP0, CSP0);
  k_cheb<<<dim3(8, 48), b, 0, stream>>>(PTP0, CSP0, HB, wsf, Y1T, nullptr, 2.f, XBT, Y3T, PTP1, CSP1);
  k_cheb<<<dim3(8, 48), b, 0, stream>>>(PTP1, CSP1, HB, wsf, Y1T, nullptr, 2.f, XBT, Y4T, PTP0, CSP0);
  k_cheb<<<dim3(8, 48), b, 0, stream>>>(PTP0, CSP0, HB, wsf, Y1T, nullptr, 2.f, XBT, Y5T, nullptr, nullptr);
  // out = x@(ts0+td0) + Z1@ts1 + Z2@ts2 + Y1@td1 + ... + Y5@td5
  k_out<<<dim3(8, 48), b, 0, stream>>>(XBT, Z1T, Z2T, Y1T, Y2T, Y3T, Y4T, Y5T, WTS, out);
}

// Round 4
// 81.172 us; speedup vs baseline: 3.1618x; 1.4960x over previous
//
#include <hip/hip_runtime.h>
#include <cstddef>
#include <cstdint>

#define NN 512
#define CC 64
#define BT 48

typedef __bf16 bf16_t;
typedef bf16_t bf16x8 __attribute__((ext_vector_type(8)));
typedef bf16_t bf16x4 __attribute__((ext_vector_type(4)));
typedef float f32x4 __attribute__((ext_vector_type(4)));

// ---- workspace float-word offsets ----
#define OFF_SC    0
#define OFF_MN    16
#define OFF_MX    3088
#define OFF_WSB   8192      // ws bf16 [512][512]
#define OFF_WS2B  139264    // ws2 bf16 [512][512]
#define OFF_XBT   270336    // x^T bf16 [48][64][512]
#define OFF_XNB   1056768   // x natural bf16 [48][512][64]
#define OFF_XNR   1843200   // x natural residual
#define OFF_HB    2629632   // H bf16 [48][512][64]
#define OFF_HR    3416064
#define OFF_P0P   4202496   // P0 partials fp32 [48][8][64][64]
#define OFF_CS0   5775360   // colsum partials fp32 [48][8][64]
#define OFF_WEB   5799936   // Weff^T bf16 [48][64][64]
#define OFF_WER   5898240
#define OFF_VDY   5996544   // v fp32 [48][64]
#define OFF_T1T   5999616   // ts1^T bf16 [64][64]
#define OFF_T2T   6001664

__device__ __forceinline__ f32x4 mfma(bf16x8 a, bf16x8 b, f32x4 c) {
  return __builtin_amdgcn_mfma_f32_16x16x32_bf16(a, b, c, 0, 0, 0);
}
__device__ __forceinline__ int swz_chunk(int r, int c8) {
  return r * 64 + ((c8 ^ (r & 7)) << 3);
}
__device__ __forceinline__ int swz_e(int r, int c) {
  return r * 64 + ((((c >> 3) ^ (r & 7)) << 3)) + (c & 7);
}
__device__ __forceinline__ bf16x8 frag(const bf16_t* sm, int row, int kc) {
  return *(const bf16x8*)(sm + row * 64 + ((kc ^ (row & 7)) << 3));
}
__device__ __forceinline__ void stage64(bf16_t* sm, const bf16_t* g, int ld, int tid) {
#pragma unroll
  for (int j = 0; j < 2; ++j) {
    int id = tid + 256 * j;
    int r = id >> 3, c8 = id & 7;
    bf16x8 v = *(const bf16x8*)(g + (size_t)r * ld + c8 * 8);
    *(bf16x8*)(sm + swz_chunk(r, c8)) = v;
  }
}
struct bfpair { bf16_t b, r; };
__device__ __forceinline__ bfpair splitbf(float f) {
  bfpair p;
  p.b = (bf16_t)f;
  p.r = (bf16_t)(f - (float)p.b);
  return p;
}

// ======================= k_prep =======================
// by<48: per (bt, n-slice): XBT, XNb/XNr, H(b/r), P0 partial, colsum partial
// by in [48,56): ws2 tile; by==56: ws->bf16; by==57: ts1/ts2 transposed bf16
__global__ __launch_bounds__(256) void k_prep(
    const float* __restrict__ x, const float* __restrict__ wsL,
    const float* __restrict__ ts, const float* __restrict__ wp,
    const float* __restrict__ td, float* __restrict__ wsf)
{
  __shared__ __align__(16) char pool[57856];
  const int tid = threadIdx.x;
  const int bx = blockIdx.x, by = blockIdx.y;
  bf16_t* WSB = (bf16_t*)(wsf + OFF_WSB);
  bf16_t* WS2B = (bf16_t*)(wsf + OFF_WS2B);

  if (by == 56) {  // ws -> bf16 rows [bx*64, +64)
    const float* wrow = wsL + (size_t)bx * 64 * 512;
    bf16_t* wob = WSB + (size_t)bx * 64 * 512;
    for (int j = 0; j < 32; ++j) {
      int idx = tid + 256 * j;
      float4 v = *(const float4*)(wrow + (size_t)idx * 4);
      bf16x4 o = {(bf16_t)v.x, (bf16_t)v.y, (bf16_t)v.z, (bf16_t)v.w};
      *(bf16x4*)(wob + (size_t)idx * 4) = o;
    }
    return;
  }
  if (by == 57) {  // weights transposed
    if (bx != 0) return;
    bf16_t* T1 = (bf16_t*)(wsf + OFF_T1T);
    bf16_t* T2 = (bf16_t*)(wsf + OFF_T2T);
    const float* t1g = ts + 4096;
    const float* t2g = ts + 8192;
    for (int j = 0; j < 16; ++j) {
      int idx = tid + 256 * j;
      int cin = idx >> 6, co = idx & 63;
      T1[co * 64 + cin] = (bf16_t)t1g[cin * 64 + co];
      T2[co * 64 + cin] = (bf16_t)t2g[cin * 64 + co];
    }
    return;
  }
  const int w = tid >> 6, l = tid & 63, lh = l >> 4, lr = l & 15, m0 = w * 16;
  if (by >= 48) {  // ws2 = 2*ws@ws - I, tile (r0, c0)
    bf16_t* Asb = (bf16_t*)pool;
    bf16_t* Asr = (bf16_t*)(pool + 8192);
    bf16_t* Bsb = (bf16_t*)(pool + 16384);
    bf16_t* Bsr = (bf16_t*)(pool + 24576);
    bf16_t* Ys  = (bf16_t*)(pool + 32768);
    const int r0 = (by - 48) * 64, c0 = bx * 64;
    f32x4 acc[4] = {};
    for (int jj = 0; jj < 8; ++jj) {
      if (jj) __syncthreads();
      for (int j = 0; j < 4; ++j) {
        int idx = tid + 256 * j;
        int r = idx >> 4, cc = (idx & 15) * 4;
        float4 v = *(const float4*)(wsL + (size_t)(r0 + r) * 512 + jj * 64 + cc);
        bfpair p0 = splitbf(v.x), p1 = splitbf(v.y), p2 = splitbf(v.z), p3 = splitbf(v.w);
        bf16x4 vb = {p0.b, p1.b, p2.b, p3.b};
        bf16x4 vr = {p0.r, p1.r, p2.r, p3.r};
        *(bf16x4*)(Asb + swz_e(r, cc)) = vb;
        *(bf16x4*)(Asr + swz_e(r, cc)) = vr;
        float4 u = *(const float4*)(wsL + (size_t)(jj * 64 + r) * 512 + c0 + cc);
        bfpair q0 = splitbf(u.x), q1 = splitbf(u.y), q2 = splitbf(u.z), q3 = splitbf(u.w);
        Bsb[swz_e(cc + 0, r)] = q0.b; Bsr[swz_e(cc + 0, r)] = q0.r;
        Bsb[swz_e(cc + 1, r)] = q1.b; Bsr[swz_e(cc + 1, r)] = q1.r;
        Bsb[swz_e(cc + 2, r)] = q2.b; Bsr[swz_e(cc + 2, r)] = q2.r;
        Bsb[swz_e(cc + 3, r)] = q3.b; Bsr[swz_e(cc + 3, r)] = q3.r;
      }
      __syncthreads();
#pragma unroll
      for (int q = 0; q < 2; ++q) {
        bf16x8 ab = frag(Asb, m0 + lr, q * 4 + lh);
        bf16x8 ar = frag(Asr, m0 + lr, q * 4 + lh);
#pragma unroll
        for (int t = 0; t < 4; ++t) {
          bf16x8 bb = frag(Bsb, t * 16 + lr, q * 4 + lh);
          bf16x8 br = frag(Bsr, t * 16 + lr, q * 4 + lh);
          acc[t] = mfma(ab, bb, acc[t]);
          acc[t] = mfma(ab, br, acc[t]);
          acc[t] = mfma(ar, bb, acc[t]);
        }
      }
    }
#pragma unroll
    for (int t = 0; t < 4; ++t)
#pragma unroll
      for (int r_ = 0; r_ < 4; ++r_) {
        int row = m0 + 4 * lh + r_, col = t * 16 + lr;
        float v = 2.0f * acc[t][r_] - ((r0 + row) == (c0 + col) ? 1.0f : 0.0f);
        Ys[swz_e(row, col)] = (bf16_t)v;
      }
    __syncthreads();
#pragma unroll
    for (int j = 0; j < 2; ++j) {
      int id = tid + 256 * j;
      int r = id >> 3, c8 = id & 7;
      *(bf16x8*)(WS2B + (size_t)(r0 + r) * 512 + c0 + c8 * 8) =
          *(const bf16x8*)(Ys + swz_chunk(r, c8));
    }
    return;
  }
  // ---- main x block ----
  float (*XsF)[66] = (float(*)[66])pool;
  bf16_t* Ab  = (bf16_t*)(pool + 16896);
  bf16_t* Ar  = (bf16_t*)(pool + 25088);
  bf16_t* Tb  = (bf16_t*)(pool + 33280);
  bf16_t* Wpb = (bf16_t*)(pool + 41472);
  bf16_t* Wpr = (bf16_t*)(pool + 49664);
  const int bt = by, i0 = bx * 64;
  bf16_t* XBT = (bf16_t*)(wsf + OFF_XBT);
  bf16_t* XNb = (bf16_t*)(wsf + OFF_XNB);
  bf16_t* XNr = (bf16_t*)(wsf + OFF_XNR);
  bf16_t* HBp = (bf16_t*)(wsf + OFF_HB);
  bf16_t* HRp = (bf16_t*)(wsf + OFF_HR);
  float* P0P = wsf + OFF_P0P;
  float* CS0 = wsf + OFF_CS0;
  const float* xg = x + ((size_t)bt * NN + i0) * CC;
  for (int j = 0; j < 4; ++j) {
    int idx = tid + 256 * j;
    int r = idx >> 4, c0v = (idx & 15) * 4;
    float4 v = *(const float4*)(xg + (size_t)r * CC + c0v);
    bfpair p0 = splitbf(v.x), p1 = splitbf(v.y), p2 = splitbf(v.z), p3 = splitbf(v.w);
    bf16x4 vb = {p0.b, p1.b, p2.b, p3.b};
    bf16x4 vr = {p0.r, p1.r, p2.r, p3.r};
    *(bf16x4*)(Ab + swz_e(r, c0v)) = vb;
    *(bf16x4*)(Ar + swz_e(r, c0v)) = vr;
    size_t gb = ((size_t)bt * 512 + i0 + r) * 64 + c0v;
    *(bf16x4*)(XNb + gb) = vb;
    *(bf16x4*)(XNr + gb) = vr;
    XsF[c0v + 0][r] = v.x; XsF[c0v + 1][r] = v.y;
    XsF[c0v + 2][r] = v.z; XsF[c0v + 3][r] = v.w;
    Tb[swz_e(c0v + 0, r)] = p0.b; Tb[swz_e(c0v + 1, r)] = p1.b;
    Tb[swz_e(c0v + 2, r)] = p2.b; Tb[swz_e(c0v + 3, r)] = p3.b;
  }
  for (int j = 0; j < 4; ++j) {
    int idx = tid + 256 * j;
    int r = idx >> 4, c0v = (idx & 15) * 4;   // r = cin
    float4 v = *(const float4*)(wp + r * 64 + c0v);
    bfpair p0 = splitbf(v.x), p1 = splitbf(v.y), p2 = splitbf(v.z), p3 = splitbf(v.w);
    Wpb[swz_e(c0v + 0, r)] = p0.b; Wpr[swz_e(c0v + 0, r)] = p0.r;
    Wpb[swz_e(c0v + 1, r)] = p1.b; Wpr[swz_e(c0v + 1, r)] = p1.r;
    Wpb[swz_e(c0v + 2, r)] = p2.b; Wpr[swz_e(c0v + 2, r)] = p2.r;
    Wpb[swz_e(c0v + 3, r)] = p3.b; Wpr[swz_e(c0v + 3, r)] = p3.r;
  }
  __syncthreads();
  {  // x^T bf16 global
    int c = tid >> 2, k0 = (tid & 3) * 16;
    bf16x8 o1, o2;
#pragma unroll
    for (int q = 0; q < 8; ++q) {
      o1[q] = (bf16_t)XsF[c][k0 + q];
      o2[q] = (bf16_t)XsF[c][k0 + 8 + q];
    }
    size_t base = ((size_t)bt * 64 + c) * 512 + i0 + k0;
    *(bf16x8*)(XBT + base) = o1; *(bf16x8*)(XBT + base + 8) = o2;
  }
  if (tid < 64) {
    float s = 0.f;
    for (int r = 0; r < 64; ++r) s += XsF[tid][r];
    CS0[((size_t)bt * 8 + bx) * 64 + tid] = s;
  }
  f32x4 accH[4] = {}; f32x4 accP[4] = {};
#pragma unroll
  for (int q = 0; q < 2; ++q) {
    bf16x8 ab = frag(Ab, m0 + lr, q * 4 + lh);
    bf16x8 ar = frag(Ar, m0 + lr, q * 4 + lh);
    bf16x8 at = frag(Tb, m0 + lr, q * 4 + lh);
#pragma unroll
    for (int t = 0; t < 4; ++t) {
      bf16x8 bb = frag(Wpb, t * 16 + lr, q * 4 + lh);
      bf16x8 br = frag(Wpr, t * 16 + lr, q * 4 + lh);
      accH[t] = mfma(ab, bb, accH[t]);
      accH[t] = mfma(ab, br, accH[t]);
      accH[t] = mfma(ar, bb, accH[t]);
      bf16x8 bt_ = frag(Tb, t * 16 + lr, q * 4 + lh);
      accP[t] = mfma(at, bt_, accP[t]);
    }
  }
  {  // P0 partial fp32
    float* po = P0P + ((size_t)bt * 8 + bx) * 4096;
#pragma unroll
    for (int t = 0; t < 4; ++t)
#pragma unroll
      for (int r_ = 0; r_ < 4; ++r_)
        po[(m0 + 4 * lh + r_) * 64 + t * 16 + lr] = accP[t][r_];
  }
  __syncthreads();
#pragma unroll
  for (int t = 0; t < 4; ++t)
#pragma unroll
    for (int r_ = 0; r_ < 4; ++r_)
      XsF[m0 + 4 * lh + r_][t * 16 + lr] = accH[t][r_];
  __syncthreads();
  {  // H natural split
    int r = tid >> 2, c0v = (tid & 3) * 16;
    bf16x8 o1, o2, q1, q2;
#pragma unroll
    for (int q = 0; q < 8; ++q) {
      bfpair a = splitbf(XsF[r][c0v + q]);
      bfpair b = splitbf(XsF[r][c0v + 8 + q]);
      o1[q] = a.b; q1[q] = a.r;
      o2[q] = b.b; q2[q] = b.r;
    }
    size_t base = ((size_t)bt * 512 + i0 + r) * 64 + c0v;
    *(bf16x8*)(HBp + base) = o1; *(bf16x8*)(HBp + base + 8) = o2;
    *(bf16x8*)(HRp + base) = q1; *(bf16x8*)(HRp + base + 8) = q2;
  }
}

// ======================= k_minmax =======================
__global__ __launch_bounds__(256) void k_minmax(float* __restrict__ wsf)
{
  __shared__ __align__(16) bf16_t Ha[4096], Hc[4096], Xa[4096], Xc[4096];
  __shared__ float red[16];
  const int tid = threadIdx.x;
  const int bx = blockIdx.x, byj = blockIdx.y, bt = blockIdx.z;
  const bf16_t* HBp = (const bf16_t*)(wsf + OFF_HB);
  const bf16_t* HRp = (const bf16_t*)(wsf + OFF_HR);
  const bf16_t* XNb = (const bf16_t*)(wsf + OFF_XNB);
  const bf16_t* XNr = (const bf16_t*)(wsf + OFF_XNR);
  stage64(Ha, HBp + ((size_t)bt * 512 + bx * 64) * 64, 64, tid);
  stage64(Hc, HRp + ((size_t)bt * 512 + bx * 64) * 64, 64, tid);
  stage64(Xa, XNb + ((size_t)bt * 512 + byj * 64) * 64, 64, tid);
  stage64(Xc, XNr + ((size_t)bt * 512 + byj * 64) * 64, 64, tid);
  __syncthreads();
  const int w = tid >> 6, l = tid & 63, lh = l >> 4, lr = l & 15, m0 = w * 16;
  f32x4 acc[4] = {};
#pragma unroll
  for (int q = 0; q < 2; ++q) {
    bf16x8 ab = frag(Ha, m0 + lr, q * 4 + lh);
    bf16x8 ar = frag(Hc, m0 + lr, q * 4 + lh);
#pragma unroll
    for (int t = 0; t < 4; ++t) {
      bf16x8 bb = frag(Xa, t * 16 + lr, q * 4 + lh);
      bf16x8 br = frag(Xc, t * 16 + lr, q * 4 + lh);
      acc[t] = mfma(ab, bb, acc[t]);
      acc[t] = mfma(ab, br, acc[t]);
      acc[t] = mfma(ar, bb, acc[t]);
    }
  }
  float mn = acc[0][0], mx = acc[0][0];
#pragma unroll
  for (int t = 0; t < 4; ++t)
#pragma unroll
    for (int r = 0; r < 4; ++r) { mn = fminf(mn, acc[t][r]); mx = fmaxf(mx, acc[t][r]); }
  for (int off = 32; off; off >>= 1) {
    mn = fminf(mn, __shfl_xor(mn, off));
    mx = fmaxf(mx, __shfl_xor(mx, off));
  }
  if (l == 0) { red[w] = mn; red[8 + w] = mx; }
  __syncthreads();
  if (tid == 0) {
    mn = fminf(fminf(red[0], red[1]), fminf(red[2], red[3]));
    mx = fmaxf(fmaxf(red[8], red[9]), fmaxf(red[10], red[11]));
    int id = (bt * 8 + byj) * 8 + bx;
    wsf[OFF_MN + id] = mn; wsf[OFF_MX + id] = mx;
  }
}

__global__ __launch_bounds__(256) void k_reduce(float* __restrict__ wsf)
{
  const int tid = threadIdx.x;
  float mn = 3.4e38f, mx = -3.4e38f;
  for (int i = tid; i < 3072; i += 256) {
    mn = fminf(mn, wsf[OFF_MN + i]);
    mx = fmaxf(mx, wsf[OFF_MX + i]);
  }
  for (int off = 32; off; off >>= 1) {
    mn = fminf(mn, __shfl_xor(mn, off));
    mx = fmaxf(mx, __shfl_xor(mx, off));
  }
  __shared__ float red[16];
  if ((tid & 63) == 0) { red[tid >> 6] = mn; red[8 + (tid >> 6)] = mx; }
  __syncthreads();
  if (tid == 0) {
    mn = fminf(fminf(red[0], red[1]), fminf(red[2], red[3]));
    mx = fmaxf(fmaxf(red[8], red[9]), fmaxf(red[10], red[11]));
    float s = 1.0f / (mx + mn) / 262144.0f;
    wsf[0] = s;
    wsf[1] = mn * s;
  }
}

// ======================= k_dyn =======================
// Per bt: closed-form 64x64 Chebyshev recurrence -> Weff^T (bf16 split) + v
__global__ __launch_bounds__(256) void k_dyn(
    const float* __restrict__ ts, const float* __restrict__ wp,
    const float* __restrict__ td, float* __restrict__ wsf)
{
  __shared__ __align__(16) char pool[116736];
  float (*P0F)[66] = (float(*)[66])pool;
  float (*WpF)[66] = (float(*)[66])(pool + 16896);
  float* uF  = (float*)(pool + 33792);
  float* bF  = uF + 64;
  float* bnF = uF + 128;
  float* hF  = uF + 192;
  bf16_t* Gb   = (bf16_t*)(pool + 34816);
  bf16_t* Gr   = (bf16_t*)(pool + 43008);
  bf16_t* ANb  = (bf16_t*)(pool + 51200);
  bf16_t* ANr  = (bf16_t*)(pool + 59392);
  bf16_t* ATb  = (bf16_t*)(pool + 67584);
  bf16_t* ATr  = (bf16_t*)(pool + 75776);
  bf16_t* Wpnb = (bf16_t*)(pool + 83968);
  bf16_t* Wpnr = (bf16_t*)(pool + 92160);
  bf16_t* R1b  = (bf16_t*)(pool + 100352);  // Wpt / Td / MT
  bf16_t* R1r  = (bf16_t*)(pool + 108544);
  const int tid = threadIdx.x;
  const int bt = blockIdx.x;
  const int w = tid >> 6, l = tid & 63, lh = l >> 4, lr = l & 15, m0 = w * 16;
  const float* P0P = wsf + OFF_P0P;
  const float* CS0 = wsf + OFF_CS0;
  const float s_sc = wsf[0], c_sc = wsf[1];

  // phase 0: gather P0, u, wp; build splits
  for (int j = 0; j < 16; ++j) {
    int idx = tid + 256 * j;
    int m = idx >> 6, jc = idx & 63;
    float v = 0.f;
#pragma unroll
    for (int p = 0; p < 8; ++p) v += P0P[((size_t)bt * 8 + p) * 4096 + idx];
    P0F[m][jc] = v;
    bfpair pp = splitbf(v);
    ANb[swz_e(m, jc)] = pp.b; ANr[swz_e(m, jc)] = pp.r;
    ATb[swz_e(jc, m)] = pp.b; ATr[swz_e(jc, m)] = pp.r;
  }
  for (int j = 0; j < 4; ++j) {
    int idx = tid + 256 * j;
    int r = idx >> 4, cc = (idx & 15) * 4;
    float4 v = *(const float4*)(wp + r * 64 + cc);
    float vv[4] = {v.x, v.y, v.z, v.w};
#pragma unroll
    for (int e = 0; e < 4; ++e) {
      WpF[r][cc + e] = vv[e];
      bfpair p = splitbf(vv[e]);
      Wpnb[swz_e(r, cc + e)] = p.b; Wpnr[swz_e(r, cc + e)] = p.r;
      R1b[swz_e(cc + e, r)] = p.b;  R1r[swz_e(cc + e, r)] = p.r;  // wp^T
    }
  }
  if (tid < 64) {
    float s = 0.f;
#pragma unroll
    for (int p = 0; p < 8; ++p) s += CS0[((size_t)bt * 8 + p) * 64 + tid];
    uF[tid] = s; bF[tid] = s;
  }
  __syncthreads();
  if (tid < 64) {
    float s = 0.f;
    for (int c = 0; c < 64; ++c) s += WpF[c][tid] * uF[c];
    hF[tid] = s;
  }
  // phase 1: G = P0 @ wp
  {
    f32x4 g[4] = {};
#pragma unroll
    for (int q = 0; q < 2; ++q) {
      bf16x8 ab = frag(ANb, m0 + lr, q * 4 + lh);
      bf16x8 ar = frag(ANr, m0 + lr, q * 4 + lh);
#pragma unroll
      for (int t = 0; t < 4; ++t) {
        bf16x8 bb = frag(R1b, t * 16 + lr, q * 4 + lh);
        bf16x8 br = frag(R1r, t * 16 + lr, q * 4 + lh);
        g[t] = mfma(ab, bb, g[t]);
        g[t] = mfma(ab, br, g[t]);
        g[t] = mfma(ar, bb, g[t]);
      }
    }
    __syncthreads();  // wp^T reads done; h done
#pragma unroll
    for (int t = 0; t < 4; ++t)
#pragma unroll
      for (int r_ = 0; r_ < 4; ++r_) {
        int m = m0 + 4 * lh + r_, p = t * 16 + lr;
        bfpair pr = splitbf(g[t][r_]);
        Gb[swz_e(m, p)] = pr.b; Gr[swz_e(m, p)] = pr.r;
      }
  }
  __syncthreads();
  // phase 2: loop i = 1..5
  float mu = 0.f;
  f32x4 Macc[4] = {};
  float vacc = 0.f;
  for (int i = 1; i <= 5; ++i) {
    const float* tdg = td + i * 4096;
    for (int j = 0; j < 16; ++j) {  // td^T split into R1
      int idx = tid + 256 * j;
      int cin = idx >> 6, co = idx & 63;
      bfpair p = splitbf(tdg[cin * 64 + co]);
      R1b[swz_e(co, cin)] = p.b; R1r[swz_e(co, cin)] = p.r;
    }
    __syncthreads();
    f32x4 Aacc[4] = {};
#pragma unroll
    for (int q = 0; q < 2; ++q) {
      bf16x8 ab = frag(ANb, m0 + lr, q * 4 + lh);
      bf16x8 ar = frag(ANr, m0 + lr, q * 4 + lh);
#pragma unroll
      for (int t = 0; t < 4; ++t) {
        bf16x8 bb = frag(R1b, t * 16 + lr, q * 4 + lh);
        bf16x8 br = frag(R1r, t * 16 + lr, q * 4 + lh);
        Macc[t] = mfma(ab, bb, Macc[t]);
        Macc[t] = mfma(ab, br, Macc[t]);
        Macc[t] = mfma(ar, bb, Macc[t]);
      }
    }
    if (tid < 64) {
      float s = 0.f;
      for (int c = 0; c < 64; ++c) s += bF[c] * tdg[c * 64 + tid];
      vacc += s;
    }
    if (i < 5) {
#pragma unroll
      for (int q = 0; q < 2; ++q) {
        bf16x8 gb = frag(Gb, m0 + lr, q * 4 + lh);
        bf16x8 gr = frag(Gr, m0 + lr, q * 4 + lh);
#pragma unroll
        for (int t = 0; t < 4; ++t) {
          bf16x8 bb = frag(ATb, t * 16 + lr, q * 4 + lh);
          bf16x8 br = frag(ATr, t * 16 + lr, q * 4 + lh);
          Aacc[t] = mfma(gb, bb, Aacc[t]);
          Aacc[t] = mfma(gb, br, Aacc[t]);
          Aacc[t] = mfma(gr, bb, Aacc[t]);
        }
      }
      if (tid < 64) {  // b_{i+1}
        int j = tid;
        float t1 = 0.f;
        for (int m = 0; m < 64; ++m)
          t1 += ((float)ANb[swz_e(m, j)] + (float)ANr[swz_e(m, j)]) * hF[m];
        bnF[j] = 2.f * (s_sc * t1 + c_sc * 512.f * bF[j] + mu * uF[j]) -
                 (i >= 2 ? uF[j] : 0.f);
      }
      __syncthreads();  // old AN/AT reads complete
#pragma unroll
      for (int t = 0; t < 4; ++t)
#pragma unroll
        for (int r_ = 0; r_ < 4; ++r_) {
          int m = m0 + 4 * lh + r_, j = t * 16 + lr;
          float v = 2.f * (s_sc * Aacc[t][r_] + c_sc * uF[m] * bF[j] + mu * P0F[m][j]) -
                    (i >= 2 ? P0F[m][j] : 0.f);
          bfpair p = splitbf(v);
          ANb[swz_e(m, j)] = p.b; ANr[swz_e(m, j)] = p.r;
          ATb[swz_e(j, m)] = p.b; ATr[swz_e(j, m)] = p.r;
        }
      __syncthreads();
      if (tid < 64) bF[tid] = bnF[tid];
      mu = (i == 1) ? -1.f : 0.f;
    }
    __syncthreads();
  }
  // phase 3: WM = wp @ M; Weff
#pragma unroll
  for (int t = 0; t < 4; ++t)
#pragma unroll
    for (int r_ = 0; r_ < 4; ++r_) {
      int m = m0 + 4 * lh + r_, co = t * 16 + lr;
      bfpair p = splitbf(Macc[t][r_]);
      R1b[swz_e(co, m)] = p.b; R1r[swz_e(co, m)] = p.r;  // M^T
    }
  __syncthreads();
  f32x4 WM[4] = {};
#pragma unroll
  for (int q = 0; q < 2; ++q) {
    bf16x8 ab = frag(Wpnb, m0 + lr, q * 4 + lh);
    bf16x8 ar = frag(Wpnr, m0 + lr, q * 4 + lh);
#pragma unroll
    for (int t = 0; t < 4; ++t) {
      bf16x8 bb = frag(R1b, t * 16 + lr, q * 4 + lh);
      bf16x8 br = frag(R1r, t * 16 + lr, q * 4 + lh);
      WM[t] = mfma(ab, bb, WM[t]);
      WM[t] = mfma(ab, br, WM[t]);
      WM[t] = mfma(ar, bb, WM[t]);
    }
  }
  bf16_t* WEb = (bf16_t*)(wsf + OFF_WEB);
  bf16_t* WEr = (bf16_t*)(wsf + OFF_WER);
  const float* td2g = td + 2 * 4096;
#pragma unroll
  for (int t = 0; t < 4; ++t)
#pragma unroll
    for (int r_ = 0; r_ < 4; ++r_) {
      int a = m0 + 4 * lh + r_, co = t * 16 + lr;
      float weff = ts[a * 64 + co] + td[a * 64 + co] - td2g[a * 64 + co] +
                   s_sc * WM[t][r_];
      bfpair p = splitbf(weff);
      WEb[((size_t)bt * 64 + co) * 64 + a] = p.b;
      WEr[((size_t)bt * 64 + co) * 64 + a] = p.r;
    }
  if (tid < 64) (wsf + OFF_VDY)[bt * 64 + tid] = c_sc * vacc;
}

// ======================= k_static_out =======================
// Z1^T/Z2^T tiles (K=512) then out = x@Weff + Z1@ts1 + Z2@ts2 + 1*v
__global__ __launch_bounds__(256) void k_static_out(
    float* __restrict__ wsf, float* __restrict__ out)
{
  __shared__ __align__(16) char pool[65536];
  bf16_t* As = (bf16_t*)pool;
  bf16_t* B1 = (bf16_t*)(pool + 8192);
  bf16_t* B2 = (bf16_t*)(pool + 16384);
  // epilogue aliases
  bf16_t* Z1s = (bf16_t*)pool;
  bf16_t* Z2s = (bf16_t*)(pool + 8192);
  bf16_t* Xb  = (bf16_t*)(pool + 16384);
  bf16_t* Xr  = (bf16_t*)(pool + 24576);
  bf16_t* WEs = (bf16_t*)(pool + 32768);
  bf16_t* WRs = (bf16_t*)(pool + 40960);
  bf16_t* T1s = (bf16_t*)(pool + 49152);
  bf16_t* T2s = (bf16_t*)(pool + 57344);
  const int tid = threadIdx.x;
  const int bx = blockIdx.x, bt = blockIdx.y;
  const int n0 = bx * 64;
  const int w = tid >> 6, l = tid & 63, lh = l >> 4, lr = l & 15, m0 = w * 16;
  const bf16_t* XBT = (const bf16_t*)(wsf + OFF_XBT);
  const bf16_t* WSB = (const bf16_t*)(wsf + OFF_WSB);
  const bf16_t* WS2B = (const bf16_t*)(wsf + OFF_WS2B);
  f32x4 acc1[4] = {}, acc2[4] = {};
  for (int kk = 0; kk < 8; ++kk) {
    if (kk) __syncthreads();
    stage64(As, XBT + (size_t)bt * 32768 + kk * 64, 512, tid);
    stage64(B1, WSB + (size_t)n0 * 512 + kk * 64, 512, tid);
    stage64(B2, WS2B + (size_t)n0 * 512 + kk * 64, 512, tid);
    __syncthreads();
#pragma unroll
    for (int q = 0; q < 2; ++q) {
      bf16x8 a = frag(As, m0 + lr, q * 4 + lh);
#pragma unroll
      for (int t = 0; t < 4; ++t) {
        acc1[t] = mfma(a, frag(B1, t * 16 + lr, q * 4 + lh), acc1[t]);
        acc2[t] = mfma(a, frag(B2, t * 16 + lr, q * 4 + lh), acc2[t]);
      }
    }
  }
  __syncthreads();  // all MFMA reads of As/B1/B2 done before aliasing
  // scatter Z^T tiles transposed -> [n][c]
#pragma unroll
  for (int t = 0; t < 4; ++t)
#pragma unroll
    for (int r_ = 0; r_ < 4; ++r_) {
      int cy = m0 + 4 * lh + r_, nl = t * 16 + lr;
      Z1s[swz_e(nl, cy)] = (bf16_t)acc1[t][r_];
      Z2s[swz_e(nl, cy)] = (bf16_t)acc2[t][r_];
    }
  stage64(Xb, (const bf16_t*)(wsf + OFF_XNB) + ((size_t)bt * 512 + n0) * 64, 64, tid);
  stage64(Xr, (const bf16_t*)(wsf + OFF_XNR) + ((size_t)bt * 512 + n0) * 64, 64, tid);
  stage64(WEs, (const bf16_t*)(wsf + OFF_WEB) + (size_t)bt * 4096, 64, tid);
  stage64(WRs, (const bf16_t*)(wsf + OFF_WER) + (size_t)bt * 4096, 64, tid);
  stage64(T1s, (const bf16_t*)(wsf + OFF_T1T), 64, tid);
  stage64(T2s, (const bf16_t*)(wsf + OFF_T2T), 64, tid);
  __syncthreads();
  const float* VDY = wsf + OFF_VDY;
  f32x4 accO[4];
#pragma unroll
  for (int t = 0; t < 4; ++t) {
    float vv = VDY[bt * 64 + t * 16 + lr];
    accO[t] = {vv, vv, vv, vv};
  }
#pragma unroll
  for (int q = 0; q < 2; ++q) {
    bf16x8 aXb = frag(Xb, m0 + lr, q * 4 + lh);
    bf16x8 aXr = frag(Xr, m0 + lr, q * 4 + lh);
    bf16x8 aZ1 = frag(Z1s, m0 + lr, q * 4 + lh);
    bf16x8 aZ2 = frag(Z2s, m0 + lr, q * 4 + lh);
#pragma unroll
    for (int t = 0; t < 4; ++t) {
      bf16x8 bWb = frag(WEs, t * 16 + lr, q * 4 + lh);
      bf16x8 bWr = frag(WRs, t * 16 + lr, q * 4 + lh);
      accO[t] = mfma(aXb, bWb, accO[t]);
      accO[t] = mfma(aXb, bWr, accO[t]);
      accO[t] = mfma(aXr, bWb, accO[t]);
      accO[t] = mfma(aZ1, frag(T1s, t * 16 + lr, q * 4 + lh), accO[t]);
      accO[t] = mfma(aZ2, frag(T2s, t * 16 + lr, q * 4 + lh), accO[t]);
    }
  }
#pragma unroll
  for (int t = 0; t < 4; ++t)
#pragma unroll
    for (int r_ = 0; r_ < 4; ++r_)
      out[((size_t)bt * 512 + n0 + m0 + 4 * lh + r_) * 64 + t * 16 + lr] = accO[t][r_];
}

extern "C" void kernel_launch(void* const* d_in, const int* in_sizes, int n_in,
                              void* d_out, int out_size, void* d_ws, size_t ws_size,
                              hipStream_t stream)
{
  (void)in_sizes; (void)n_in; (void)out_size; (void)ws_size;
  const float* x   = (const float*)d_in[0];
  const float* wsL = (const float*)d_in[1];
  const float* ts  = (const float*)d_in[2];
  const float* wp  = (const float*)d_in[3];
  const float* td  = (const float*)d_in[4];
  float* out = (float*)d_out;
  float* wsf = (float*)d_ws;
  dim3 b(256);

  k_prep      <<<dim3(8, 58),    b, 0, stream>>>(x, wsL, ts, wp, td, wsf);
  k_minmax    <<<dim3(8, 8, 48), b, 0, stream>>>(wsf);
  k_reduce    <<<1,              b, 0, stream>>>(wsf);
  k_dyn       <<<48,             b, 0, stream>>>(ts, wp, td, wsf);
  k_static_out<<<dim3(8, 48),    b, 0, stream>>>(wsf, out);
}

// Round 5
// 57.137 us; speedup vs baseline: 4.4918x; 1.4206x over previous
//
#include <hip/hip_runtime.h>
#include <cstddef>
#include <cstdint>

#define NN 512
#define CC 64
#define BT 48

typedef __bf16 bf16_t;
typedef bf16_t bf16x8 __attribute__((ext_vector_type(8)));
typedef bf16_t bf16x4 __attribute__((ext_vector_type(4)));
typedef float f32x4 __attribute__((ext_vector_type(4)));

// ---- workspace float-word offsets ----
#define OFF_MN    0         // 384 block-mins
#define OFF_MX    384       // 384 block-maxs
#define OFF_WSB   1024      // ws bf16 [512][512]
#define OFF_WS2B  132096    // ws2 bf16 [512][512]
#define OFF_XBT   263168    // x^T bf16 [48][64][512]
#define OFF_XNB   1049600   // x natural bf16 [48][512][64]
#define OFF_XNR   1836032   // x natural residual bf16
#define OFF_P0P   2622464   // P0 partials f32 [48][8][64][64]
#define OFF_CS0   4195328   // colsum partials f32 [48][8][64]
#define OFF_Z1N   4219904   // Z1 natural bf16 [48][512][64]
#define OFF_Z2N   5006336   // Z2 natural bf16
#define OFF_WEB   5792768   // Weff^T bf16 [48][64][64]
#define OFF_WER   5891072   // residual
#define OFF_VDY   5989376   // v f32 [48][64]
#define OFF_T1T   5992448   // ts1^T bf16 [64][64]
#define OFF_T2T   5994496   // ts2^T bf16 [64][64]

__device__ __forceinline__ f32x4 mfma(bf16x8 a, bf16x8 b, f32x4 c) {
  return __builtin_amdgcn_mfma_f32_16x16x32_bf16(a, b, c, 0, 0, 0);
}
__device__ __forceinline__ int swz_chunk(int r, int c8) {
  return r * 64 + ((c8 ^ (r & 7)) << 3);
}
__device__ __forceinline__ int swz_e(int r, int c) {
  return r * 64 + ((((c >> 3) ^ (r & 7)) << 3)) + (c & 7);
}
__device__ __forceinline__ bf16x8 frag(const bf16_t* sm, int row, int kc) {
  return *(const bf16x8*)(sm + row * 64 + ((kc ^ (row & 7)) << 3));
}
__device__ __forceinline__ void stage64(bf16_t* sm, const bf16_t* g, int ld, int tid) {
#pragma unroll
  for (int j = 0; j < 2; ++j) {
    int id = tid + 256 * j;
    int r = id >> 3, c8 = id & 7;
    bf16x8 v = *(const bf16x8*)(g + (size_t)r * ld + c8 * 8);
    *(bf16x8*)(sm + swz_chunk(r, c8)) = v;
  }
}
struct bfpair { bf16_t b, r; };
__device__ __forceinline__ bfpair splitbf(float f) {
  bfpair p;
  p.b = (bf16_t)f;
  p.r = (bf16_t)(f - (float)p.b);
  return p;
}

// ======================= k_prep =======================
// by<48: x blocks (XNb/XNr/XBT, P0 partial, colsum partial)
// by 48..55: ws2 = 2*ws@ws - I tiles (single-bf16)
// by==56: ws->bf16 ; by==57: ts1^T/ts2^T
__global__ __launch_bounds__(256) void k_prep(
    const float* __restrict__ x, const float* __restrict__ wsL,
    const float* __restrict__ ts, const float* __restrict__ wp,
    const float* __restrict__ td, float* __restrict__ wsf)
{
  __shared__ __align__(16) char pool[25088];
  const int tid = threadIdx.x;
  const int bx = blockIdx.x, by = blockIdx.y;
  const int w = tid >> 6, l = tid & 63, lh = l >> 4, lr = l & 15, m0 = w * 16;
  bf16_t* WSB = (bf16_t*)(wsf + OFF_WSB);
  bf16_t* WS2B = (bf16_t*)(wsf + OFF_WS2B);

  if (by == 56) {
    const float* wrow = wsL + (size_t)bx * 64 * 512;
    bf16_t* wob = WSB + (size_t)bx * 64 * 512;
    for (int j = 0; j < 32; ++j) {
      int idx = tid + 256 * j;
      float4 v = *(const float4*)(wrow + (size_t)idx * 4);
      bf16x4 o = {(bf16_t)v.x, (bf16_t)v.y, (bf16_t)v.z, (bf16_t)v.w};
      *(bf16x4*)(wob + (size_t)idx * 4) = o;
    }
    return;
  }
  if (by == 57) {
    if (bx != 0) return;
    bf16_t* T1 = (bf16_t*)(wsf + OFF_T1T);
    bf16_t* T2 = (bf16_t*)(wsf + OFF_T2T);
    const float* t1g = ts + 4096;
    const float* t2g = ts + 8192;
    for (int j = 0; j < 16; ++j) {
      int idx = tid + 256 * j;
      int cin = idx >> 6, co = idx & 63;
      T1[co * 64 + cin] = (bf16_t)t1g[cin * 64 + co];
      T2[co * 64 + cin] = (bf16_t)t2g[cin * 64 + co];
    }
    return;
  }
  if (by >= 48) {  // ws2 tile (r0, c0), single-bf16 product
    bf16_t* Asb = (bf16_t*)pool;
    bf16_t* Bsb = (bf16_t*)(pool + 8192);
    bf16_t* Ys  = (bf16_t*)(pool + 16384);
    const int r0 = (by - 48) * 64, c0 = bx * 64;
    f32x4 acc[4] = {};
    for (int jj = 0; jj < 8; ++jj) {
      if (jj) __syncthreads();
      for (int j = 0; j < 4; ++j) {
        int idx = tid + 256 * j;
        int r = idx >> 4, cc = (idx & 15) * 4;
        float4 v = *(const float4*)(wsL + (size_t)(r0 + r) * 512 + jj * 64 + cc);
        bf16x4 vb = {(bf16_t)v.x, (bf16_t)v.y, (bf16_t)v.z, (bf16_t)v.w};
        *(bf16x4*)(Asb + swz_e(r, cc)) = vb;
        float4 u = *(const float4*)(wsL + (size_t)(jj * 64 + r) * 512 + c0 + cc);
        Bsb[swz_e(cc + 0, r)] = (bf16_t)u.x;
        Bsb[swz_e(cc + 1, r)] = (bf16_t)u.y;
        Bsb[swz_e(cc + 2, r)] = (bf16_t)u.z;
        Bsb[swz_e(cc + 3, r)] = (bf16_t)u.w;
      }
      __syncthreads();
#pragma unroll
      for (int q = 0; q < 2; ++q) {
        bf16x8 a = frag(Asb, m0 + lr, q * 4 + lh);
#pragma unroll
        for (int t = 0; t < 4; ++t)
          acc[t] = mfma(a, frag(Bsb, t * 16 + lr, q * 4 + lh), acc[t]);
      }
    }
#pragma unroll
    for (int t = 0; t < 4; ++t)
#pragma unroll
      for (int r_ = 0; r_ < 4; ++r_) {
        int row = m0 + 4 * lh + r_, col = t * 16 + lr;
        float v = 2.0f * acc[t][r_] - ((r0 + row) == (c0 + col) ? 1.0f : 0.0f);
        Ys[swz_e(row, col)] = (bf16_t)v;
      }
    __syncthreads();
#pragma unroll
    for (int j = 0; j < 2; ++j) {
      int id = tid + 256 * j;
      int r = id >> 3, c8 = id & 7;
      *(bf16x8*)(WS2B + (size_t)(r0 + r) * 512 + c0 + c8 * 8) =
          *(const bf16x8*)(Ys + swz_chunk(r, c8));
    }
    return;
  }
  // ---- x block ----
  float (*XsF)[66] = (float(*)[66])pool;
  bf16_t* Tb = (bf16_t*)(pool + 16896);
  const int bt = by, i0 = bx * 64;
  bf16_t* XBT = (bf16_t*)(wsf + OFF_XBT);
  bf16_t* XNb = (bf16_t*)(wsf + OFF_XNB);
  bf16_t* XNr = (bf16_t*)(wsf + OFF_XNR);
  float* P0P = wsf + OFF_P0P;
  float* CS0 = wsf + OFF_CS0;
  const float* xg = x + ((size_t)bt * NN + i0) * CC;
  for (int j = 0; j < 4; ++j) {
    int idx = tid + 256 * j;
    int r = idx >> 4, c0v = (idx & 15) * 4;
    float4 v = *(const float4*)(xg + (size_t)r * CC + c0v);
    bfpair p0 = splitbf(v.x), p1 = splitbf(v.y), p2 = splitbf(v.z), p3 = splitbf(v.w);
    bf16x4 vb = {p0.b, p1.b, p2.b, p3.b};
    bf16x4 vr = {p0.r, p1.r, p2.r, p3.r};
    size_t gb = ((size_t)bt * 512 + i0 + r) * 64 + c0v;
    *(bf16x4*)(XNb + gb) = vb;
    *(bf16x4*)(XNr + gb) = vr;
    XsF[c0v + 0][r] = v.x; XsF[c0v + 1][r] = v.y;
    XsF[c0v + 2][r] = v.z; XsF[c0v + 3][r] = v.w;
    Tb[swz_e(c0v + 0, r)] = p0.b; Tb[swz_e(c0v + 1, r)] = p1.b;
    Tb[swz_e(c0v + 2, r)] = p2.b; Tb[swz_e(c0v + 3, r)] = p3.b;
  }
  __syncthreads();
  {  // x^T bf16 global
    int c = tid >> 2, k0 = (tid & 3) * 16;
    bf16x8 o1, o2;
#pragma unroll
    for (int q = 0; q < 8; ++q) {
      o1[q] = (bf16_t)XsF[c][k0 + q];
      o2[q] = (bf16_t)XsF[c][k0 + 8 + q];
    }
    size_t base = ((size_t)bt * 64 + c) * 512 + i0 + k0;
    *(bf16x8*)(XBT + base) = o1; *(bf16x8*)(XBT + base + 8) = o2;
  }
  if (tid < 64) {
    float s = 0.f;
    for (int r = 0; r < 64; ++r) s += XsF[tid][r];
    CS0[((size_t)bt * 8 + bx) * 64 + tid] = s;
  }
  f32x4 accP[4] = {};
#pragma unroll
  for (int q = 0; q < 2; ++q) {
    bf16x8 at = frag(Tb, m0 + lr, q * 4 + lh);
#pragma unroll
    for (int t = 0; t < 4; ++t)
      accP[t] = mfma(at, frag(Tb, t * 16 + lr, q * 4 + lh), accP[t]);
  }
  {
    float* po = P0P + ((size_t)bt * 8 + bx) * 4096;
#pragma unroll
    for (int t = 0; t < 4; ++t)
#pragma unroll
      for (int r_ = 0; r_ < 4; ++r_)
        po[(m0 + 4 * lh + r_) * 64 + t * 16 + lr] = accP[t][r_];
  }
}

// ======================= k_mmz =======================
// bid<384: minmax strip (H=x@wp inline, loop 8 x-tiles)
// bid>=384: Z1/Z2 K=512 GEMM tiles
__global__ __launch_bounds__(256) void k_mmz(const float* __restrict__ wp,
                                             float* __restrict__ wsf)
{
  __shared__ __align__(16) char pool[32768];
  __shared__ float red[16];
  const int tid = threadIdx.x;
  const int bid = blockIdx.x;
  const int w = tid >> 6, l = tid & 63, lh = l >> 4, lr = l & 15, m0 = w * 16;
  if (bid < 384) {
    const int bt = bid >> 3, bx = bid & 7;
    bf16_t* WpT = (bf16_t*)pool;
    bf16_t* Xa  = (bf16_t*)(pool + 8192);
    bf16_t* Hs  = (bf16_t*)(pool + 16384);
    bf16_t* Xb  = (bf16_t*)(pool + 24576);
    const bf16_t* XNb = (const bf16_t*)(wsf + OFF_XNB);
    for (int j = 0; j < 4; ++j) {
      int idx = tid + 256 * j;
      int r = idx >> 4, cc = (idx & 15) * 4;   // r = cin, cc = cout
      float4 v = *(const float4*)(wp + r * 64 + cc);
      WpT[swz_e(cc + 0, r)] = (bf16_t)v.x;
      WpT[swz_e(cc + 1, r)] = (bf16_t)v.y;
      WpT[swz_e(cc + 2, r)] = (bf16_t)v.z;
      WpT[swz_e(cc + 3, r)] = (bf16_t)v.w;
    }
    stage64(Xa, XNb + ((size_t)bt * 512 + bx * 64) * 64, 64, tid);
    __syncthreads();
    f32x4 hacc[4] = {};
#pragma unroll
    for (int q = 0; q < 2; ++q) {
      bf16x8 a = frag(Xa, m0 + lr, q * 4 + lh);
#pragma unroll
      for (int t = 0; t < 4; ++t)
        hacc[t] = mfma(a, frag(WpT, t * 16 + lr, q * 4 + lh), hacc[t]);
    }
#pragma unroll
    for (int t = 0; t < 4; ++t)
#pragma unroll
      for (int r_ = 0; r_ < 4; ++r_)
        Hs[swz_e(m0 + 4 * lh + r_, t * 16 + lr)] = (bf16_t)hacc[t][r_];
    float mn = 3.4e38f, mx = -3.4e38f;
    for (int byj = 0; byj < 8; ++byj) {
      __syncthreads();   // Hs writes (first) / prev MFMA reads of Xb done
      stage64(Xb, XNb + ((size_t)bt * 512 + byj * 64) * 64, 64, tid);
      __syncthreads();
      f32x4 acc[4] = {};
#pragma unroll
      for (int q = 0; q < 2; ++q) {
        bf16x8 a = frag(Hs, m0 + lr, q * 4 + lh);
#pragma unroll
        for (int t = 0; t < 4; ++t)
          acc[t] = mfma(a, frag(Xb, t * 16 + lr, q * 4 + lh), acc[t]);
      }
#pragma unroll
      for (int t = 0; t < 4; ++t)
#pragma unroll
        for (int r_ = 0; r_ < 4; ++r_) {
          mn = fminf(mn, acc[t][r_]); mx = fmaxf(mx, acc[t][r_]);
        }
    }
    for (int off = 32; off; off >>= 1) {
      mn = fminf(mn, __shfl_xor(mn, off));
      mx = fmaxf(mx, __shfl_xor(mx, off));
    }
    if (l == 0) { red[w] = mn; red[8 + w] = mx; }
    __syncthreads();
    if (tid == 0) {
      mn = fminf(fminf(red[0], red[1]), fminf(red[2], red[3]));
      mx = fmaxf(fmaxf(red[8], red[9]), fmaxf(red[10], red[11]));
      wsf[OFF_MN + bid] = mn; wsf[OFF_MX + bid] = mx;
    }
  } else {
    const int zb = bid - 384;
    const int bt = zb >> 3, n0 = (zb & 7) * 64;
    bf16_t* As = (bf16_t*)pool;
    bf16_t* B1 = (bf16_t*)(pool + 8192);
    bf16_t* B2 = (bf16_t*)(pool + 16384);
    const bf16_t* XBT = (const bf16_t*)(wsf + OFF_XBT);
    const bf16_t* WSB = (const bf16_t*)(wsf + OFF_WSB);
    const bf16_t* WS2B = (const bf16_t*)(wsf + OFF_WS2B);
    f32x4 acc1[4] = {}, acc2[4] = {};
    for (int kk = 0; kk < 8; ++kk) {
      if (kk) __syncthreads();
      stage64(As, XBT + (size_t)bt * 32768 + kk * 64, 512, tid);
      stage64(B1, WSB + (size_t)n0 * 512 + kk * 64, 512, tid);
      stage64(B2, WS2B + (size_t)n0 * 512 + kk * 64, 512, tid);
      __syncthreads();
#pragma unroll
      for (int q = 0; q < 2; ++q) {
        bf16x8 a = frag(As, m0 + lr, q * 4 + lh);
#pragma unroll
        for (int t = 0; t < 4; ++t) {
          acc1[t] = mfma(a, frag(B1, t * 16 + lr, q * 4 + lh), acc1[t]);
          acc2[t] = mfma(a, frag(B2, t * 16 + lr, q * 4 + lh), acc2[t]);
        }
      }
    }
    __syncthreads();
    // scatter transposed -> natural [n][c] tiles (reuse As/B1)
#pragma unroll
    for (int t = 0; t < 4; ++t)
#pragma unroll
      for (int r_ = 0; r_ < 4; ++r_) {
        int cy = m0 + 4 * lh + r_, nl = t * 16 + lr;
        As[swz_e(nl, cy)] = (bf16_t)acc1[t][r_];
        B1[swz_e(nl, cy)] = (bf16_t)acc2[t][r_];
      }
    __syncthreads();
    bf16_t* Z1N = (bf16_t*)(wsf + OFF_Z1N);
    bf16_t* Z2N = (bf16_t*)(wsf + OFF_Z2N);
#pragma unroll
    for (int j = 0; j < 2; ++j) {
      int id = tid + 256 * j;
      int r = id >> 3, c8 = id & 7;
      size_t gb = ((size_t)bt * 512 + n0 + r) * 64 + c8 * 8;
      *(bf16x8*)(Z1N + gb) = *(const bf16x8*)(As + swz_chunk(r, c8));
      *(bf16x8*)(Z2N + gb) = *(const bf16x8*)(B1 + swz_chunk(r, c8));
    }
  }
}

// ======================= k_dyn =======================
// Per bt: global min/max reduce + closed-form 64x64 recurrence -> Weff, v
__global__ __launch_bounds__(256) void k_dyn(
    const float* __restrict__ ts, const float* __restrict__ wp,
    const float* __restrict__ td, float* __restrict__ wsf)
{
  __shared__ __align__(16) float P0F[64][66];
  __shared__ __align__(16) bf16_t Ab[4096], ATb[4096], Gb[4096];
  __shared__ __align__(16) bf16_t tdT[5][4096];
  __shared__ __align__(16) bf16_t WpT[4096], WpN[4096];
  __shared__ float uF[64], hF[64], t1F[64], b0[64], b1[64];
  __shared__ float red[16];
  const int tid = threadIdx.x;
  const int bt = blockIdx.x;
  const int w = tid >> 6, l = tid & 63, lh = l >> 4, lr = l & 15, m0 = w * 16;
  const float* P0P = wsf + OFF_P0P;
  const float* CS0 = wsf + OFF_CS0;

  {  // global min/max partial reduce
    float mn = 3.4e38f, mx = -3.4e38f;
    for (int i = tid; i < 384; i += 256) {
      mn = fminf(mn, wsf[OFF_MN + i]);
      mx = fmaxf(mx, wsf[OFF_MX + i]);
    }
    for (int off = 32; off; off >>= 1) {
      mn = fminf(mn, __shfl_xor(mn, off));
      mx = fmaxf(mx, __shfl_xor(mx, off));
    }
    if (l == 0) { red[w] = mn; red[8 + w] = mx; }
  }
  for (int j = 0; j < 16; ++j) {  // P0 gather + A1/A1^T
    int idx = tid + 256 * j;
    int m = idx >> 6, jc = idx & 63;
    float v = 0.f;
#pragma unroll
    for (int p = 0; p < 8; ++p) v += P0P[((size_t)bt * 8 + p) * 4096 + idx];
    P0F[m][jc] = v;
    bf16_t bv = (bf16_t)v;
    Ab[swz_e(m, jc)] = bv; ATb[swz_e(jc, m)] = bv;
  }
  if (tid < 64) {
    float s = 0.f;
#pragma unroll
    for (int p = 0; p < 8; ++p) s += CS0[((size_t)bt * 8 + p) * 64 + tid];
    uF[tid] = s; b0[tid] = s;
  }
  for (int j = 0; j < 4; ++j) {  // wp natural + transposed bf16
    int idx = tid + 256 * j;
    int r = idx >> 4, cc = (idx & 15) * 4;
    float4 v = *(const float4*)(wp + r * 64 + cc);
    bf16_t q0 = (bf16_t)v.x, q1 = (bf16_t)v.y, q2 = (bf16_t)v.z, q3 = (bf16_t)v.w;
    WpN[swz_e(r, cc + 0)] = q0; WpT[swz_e(cc + 0, r)] = q0;
    WpN[swz_e(r, cc + 1)] = q1; WpT[swz_e(cc + 1, r)] = q1;
    WpN[swz_e(r, cc + 2)] = q2; WpT[swz_e(cc + 2, r)] = q2;
    WpN[swz_e(r, cc + 3)] = q3; WpT[swz_e(cc + 3, r)] = q3;
  }
  for (int i5 = 0; i5 < 5; ++i5)  // all 5 td^T tiles
    for (int j = 0; j < 4; ++j) {
      int idx = tid + 256 * j;
      int cin = idx >> 4, co = (idx & 15) * 4;
      float4 v = *(const float4*)(td + (i5 + 1) * 4096 + cin * 64 + co);
      tdT[i5][swz_e(co + 0, cin)] = (bf16_t)v.x;
      tdT[i5][swz_e(co + 1, cin)] = (bf16_t)v.y;
      tdT[i5][swz_e(co + 2, cin)] = (bf16_t)v.z;
      tdT[i5][swz_e(co + 3, cin)] = (bf16_t)v.w;
    }
  __syncthreads();
  const float mnA = fminf(fminf(red[0], red[1]), fminf(red[2], red[3]));
  const float mxA = fmaxf(fmaxf(red[8], red[9]), fmaxf(red[10], red[11]));
  const float s_sc = 1.0f / (mxA + mnA) / 262144.0f;
  const float c_sc = mnA * s_sc;
  if (tid < 64) {  // h = wp^T u
    float s = 0.f;
    for (int c = 0; c < 64; ++c) s += (float)WpT[swz_e(tid, c)] * uF[c];
    hF[tid] = s;
  }
  {  // G = P0 @ wp
    f32x4 g[4] = {};
#pragma unroll
    for (int q = 0; q < 2; ++q) {
      bf16x8 a = frag(Ab, m0 + lr, q * 4 + lh);
#pragma unroll
      for (int t = 0; t < 4; ++t)
        g[t] = mfma(a, frag(WpT, t * 16 + lr, q * 4 + lh), g[t]);
    }
#pragma unroll
    for (int t = 0; t < 4; ++t)
#pragma unroll
      for (int r_ = 0; r_ < 4; ++r_)
        Gb[swz_e(m0 + 4 * lh + r_, t * 16 + lr)] = (bf16_t)g[t][r_];
  }
  float mu = 0.f, vacc = 0.f;
  f32x4 Macc[4] = {};
  for (int i = 1; i <= 5; ++i) {
    __syncthreads();  // Gb/hF (i=1) or Anew/bnext (i>1) visible
    const float* bcur = (i & 1) ? b0 : b1;
    float* bnext = (i & 1) ? b1 : b0;
    const bf16_t* tdc = tdT[i - 1];
#pragma unroll
    for (int q = 0; q < 2; ++q) {
      bf16x8 a = frag(Ab, m0 + lr, q * 4 + lh);
#pragma unroll
      for (int t = 0; t < 4; ++t)
        Macc[t] = mfma(a, frag(tdc, t * 16 + lr, q * 4 + lh), Macc[t]);
    }
    f32x4 Aacc[4] = {};
    if (i < 5) {
#pragma unroll
      for (int q = 0; q < 2; ++q) {
        bf16x8 g = frag(Gb, m0 + lr, q * 4 + lh);
#pragma unroll
        for (int t = 0; t < 4; ++t)
          Aacc[t] = mfma(g, frag(ATb, t * 16 + lr, q * 4 + lh), Aacc[t]);
      }
    }
    if (tid < 64) {  // vacc += td_i^T b_i   (wave 0)
      float sv = 0.f;
      for (int c = 0; c < 64; ++c) sv += bcur[c] * (float)tdc[swz_e(tid, c)];
      vacc += sv;
    }
    if (i < 5 && tid >= 64 && tid < 128) {  // t1 = A_i^T h   (wave 1)
      int j = tid - 64;
      float t1 = 0.f;
      for (int m = 0; m < 64; ++m) t1 += (float)ATb[swz_e(j, m)] * hF[m];
      t1F[j] = t1;
    }
    __syncthreads();
    if (i < 5) {
#pragma unroll
      for (int t = 0; t < 4; ++t)
#pragma unroll
        for (int r_ = 0; r_ < 4; ++r_) {
          int m = m0 + 4 * lh + r_, j = t * 16 + lr;
          float v = 2.f * (s_sc * Aacc[t][r_] + c_sc * uF[m] * bcur[j] + mu * P0F[m][j])
                    - (i >= 2 ? P0F[m][j] : 0.f);
          bf16_t bv = (bf16_t)v;
          Ab[swz_e(m, j)] = bv; ATb[swz_e(j, m)] = bv;
        }
      if (tid < 64)
        bnext[tid] = 2.f * (s_sc * t1F[tid] + 512.f * c_sc * bcur[tid] + mu * uF[tid])
                     - (i >= 2 ? uF[tid] : 0.f);
      mu = (i == 1) ? -1.f : 0.f;
    }
  }
  // phase 3: WM = wp @ M ; Weff = ts0 + td0 - td2 + s*WM
#pragma unroll
  for (int t = 0; t < 4; ++t)
#pragma unroll
    for (int r_ = 0; r_ < 4; ++r_)
      Gb[swz_e(t * 16 + lr, m0 + 4 * lh + r_)] = (bf16_t)Macc[t][r_];  // M^T
  __syncthreads();
  f32x4 wm[4] = {};
#pragma unroll
  for (int q = 0; q < 2; ++q) {
    bf16x8 a = frag(WpN, m0 + lr, q * 4 + lh);
#pragma unroll
    for (int t = 0; t < 4; ++t)
      wm[t] = mfma(a, frag(Gb, t * 16 + lr, q * 4 + lh), wm[t]);
  }
  bf16_t* WEb = (bf16_t*)(wsf + OFF_WEB);
  bf16_t* WEr = (bf16_t*)(wsf + OFF_WER);
#pragma unroll
  for (int t = 0; t < 4; ++t)
#pragma unroll
    for (int r_ = 0; r_ < 4; ++r_) {
      int a_ = m0 + 4 * lh + r_, co = t * 16 + lr;
      float weff = ts[a_ * 64 + co] + td[a_ * 64 + co] - td[2 * 4096 + a_ * 64 + co]
                   + s_sc * wm[t][r_];
      bfpair p = splitbf(weff);
      WEb[((size_t)bt * 64 + co) * 64 + a_] = p.b;
      WEr[((size_t)bt * 64 + co) * 64 + a_] = p.r;
    }
  if (tid < 64) (wsf + OFF_VDY)[bt * 64 + tid] = c_sc * vacc;
}

// ======================= k_epi =======================
// out = x@Weff (split) + Z1@ts1 + Z2@ts2 + 1*v
__global__ __launch_bounds__(256) void k_epi(float* __restrict__ wsf,
                                             float* __restrict__ out)
{
  __shared__ __align__(16) bf16_t Xb[4096], Xr[4096], Z1s[4096], Z2s[4096],
                                  WEs[4096], WRs[4096], T1s[4096], T2s[4096];
  const int tid = threadIdx.x;
  const int bx = blockIdx.x, bt = blockIdx.y;
  const int n0 = bx * 64;
  const int w = tid >> 6, l = tid & 63, lh = l >> 4, lr = l & 15, m0 = w * 16;
  stage64(Xb,  (const bf16_t*)(wsf + OFF_XNB) + ((size_t)bt * 512 + n0) * 64, 64, tid);
  stage64(Xr,  (const bf16_t*)(wsf + OFF_XNR) + ((size_t)bt * 512 + n0) * 64, 64, tid);
  stage64(Z1s, (const bf16_t*)(wsf + OFF_Z1N) + ((size_t)bt * 512 + n0) * 64, 64, tid);
  stage64(Z2s, (const bf16_t*)(wsf + OFF_Z2N) + ((size_t)bt * 512 + n0) * 64, 64, tid);
  stage64(WEs, (const bf16_t*)(wsf + OFF_WEB) + (size_t)bt * 4096, 64, tid);
  stage64(WRs, (const bf16_t*)(wsf + OFF_WER) + (size_t)bt * 4096, 64, tid);
  stage64(T1s, (const bf16_t*)(wsf + OFF_T1T), 64, tid);
  stage64(T2s, (const bf16_t*)(wsf + OFF_T2T), 64, tid);
  __syncthreads();
  const float* VDY = wsf + OFF_VDY;
  f32x4 accO[4];
#pragma unroll
  for (int t = 0; t < 4; ++t) {
    float vv = VDY[bt * 64 + t * 16 + lr];
    accO[t] = {vv, vv, vv, vv};
  }
#pragma unroll
  for (int q = 0; q < 2; ++q) {
    bf16x8 aXb = frag(Xb, m0 + lr, q * 4 + lh);
    bf16x8 aXr = frag(Xr, m0 + lr, q * 4 + lh);
    bf16x8 aZ1 = frag(Z1s, m0 + lr, q * 4 + lh);
    bf16x8 aZ2 = frag(Z2s, m0 + lr, q * 4 + lh);
#pragma unroll
    for (int t = 0; t < 4; ++t) {
      bf16x8 bWb = frag(WEs, t * 16 + lr, q * 4 + lh);
      bf16x8 bWr = frag(WRs, t * 16 + lr, q * 4 + lh);
      accO[t] = mfma(aXb, bWb, accO[t]);
      accO[t] = mfma(aXb, bWr, accO[t]);
      accO[t] = mfma(aXr, bWb, accO[t]);
      accO[t] = mfma(aZ1, frag(T1s, t * 16 + lr, q * 4 + lh), accO[t]);
      accO[t] = mfma(aZ2, frag(T2s, t * 16 + lr, q * 4 + lh), accO[t]);
    }
  }
#pragma unroll
  for (int t = 0; t < 4; ++t)
#pragma unroll
    for (int r_ = 0; r_ < 4; ++r_)
      out[((size_t)bt * 512 + n0 + m0 + 4 * lh + r_) * 64 + t * 16 + lr] = accO[t][r_];
}

extern "C" void kernel_launch(void* const* d_in, const int* in_sizes, int n_in,
                              void* d_out, int out_size, void* d_ws, size_t ws_size,
                              hipStream_t stream)
{
  (void)in_sizes; (void)n_in; (void)out_size; (void)ws_size;
  const float* x   = (const float*)d_in[0];
  const float* wsL = (const float*)d_in[1];
  const float* ts  = (const float*)d_in[2];
  const float* wp  = (const float*)d_in[3];
  const float* td  = (const float*)d_in[4];
  float* out = (float*)d_out;
  float* wsf = (float*)d_ws;
  dim3 b(256);

  k_prep<<<dim3(8, 58), b, 0, stream>>>(x, wsL, ts, wp, td, wsf);
  k_mmz <<<768,         b, 0, stream>>>(wp, wsf);
  k_dyn <<<48,          b, 0, stream>>>(ts, wp, td, wsf);
  k_epi <<<dim3(8, 48), b, 0, stream>>>(wsf, out);
}